// Round 1
// baseline (297.298 us; speedup 1.0000x reference)
//
#include <hip/hip_runtime.h>

constexpr int Bb = 8;     // batch
constexpr int Nn = 1024;  // nodes
constexpr int Cc = 256;   // channels
constexpr int Hh = 4;     // heads

// ---------------------------------------------------------------------------
// Transpose [B,N,C] -> [B,C,N]. grid (N/64, C/64, B), block 256.
// ---------------------------------------------------------------------------
__global__ __launch_bounds__(256) void k_transpose(const float* __restrict__ in,
                                                   float* __restrict__ out) {
  __shared__ float tile[64][65];
  const int b = blockIdx.z, n0 = blockIdx.x * 64, c0 = blockIdx.y * 64;
  const int t = threadIdx.x;
  const int lo = t & 63, hi = t >> 6;
#pragma unroll
  for (int r = 0; r < 16; ++r) {
    int nl = hi + 4 * r;
    tile[nl][lo] = in[((b * Nn + n0 + nl) * Cc) + c0 + lo];
  }
  __syncthreads();
#pragma unroll
  for (int r = 0; r < 16; ++r) {
    int cl = hi + 4 * r;
    out[((b * Cc + c0 + cl) * Nn) + n0 + lo] = tile[lo][cl];
  }
}

// ---------------------------------------------------------------------------
// qt/kt projection. xT is [B,C,N]. W is [H, 2C+4] = [Wq | Wk | Wsq | Wsk].
// qt[b,h,n] = x[b,n,:].Wq[h] + spat.Wsq[h] + bias[h]; kt similar (no bias).
// grid (N/64, B), block 256 = 64 nodes x 4 heads.
// ---------------------------------------------------------------------------
__global__ __launch_bounds__(256) void k_qkt(const float* __restrict__ xT,
                                             const float* __restrict__ spat,
                                             const float* __restrict__ W,
                                             const float* __restrict__ bias,
                                             float* __restrict__ qt,
                                             float* __restrict__ kt) {
  __shared__ float Ws[4 * 516];
  const int b = blockIdx.y, n0 = blockIdx.x * 64;
  const int t = threadIdx.x;
  for (int idx = t; idx < 4 * 516; idx += 256) Ws[idx] = W[idx];
  __syncthreads();
  const int h = t >> 6, nl = t & 63, n = n0 + nl;
  const float* wq = &Ws[h * 516];
  const float* wk = wq + Cc;
  float qa = 0.f, ka = 0.f;
#pragma unroll 8
  for (int c = 0; c < Cc; ++c) {
    float xv = xT[((b * Cc + c) * Nn) + n];
    qa = fmaf(xv, wq[c], qa);
    ka = fmaf(xv, wk[c], ka);
  }
  const float s0 = spat[(b * Nn + n) * 2 + 0];
  const float s1 = spat[(b * Nn + n) * 2 + 1];
  qa += s0 * wq[2 * Cc + 0] + s1 * wq[2 * Cc + 1];  // Wsq
  ka += s0 * wq[2 * Cc + 2] + s1 * wq[2 * Cc + 3];  // Wsk
  qt[(b * Hh + h) * Nn + n] = qa + bias[h];         // fold logit bias into qt
  kt[(b * Hh + h) * Nn + n] = ka;
}

// ---------------------------------------------------------------------------
// Grouped 1x1 conv + ReLU. xT [B,C,N] -> out [B,C,N]. cw [G=4][64][64].
// grid (N/64, 2 o-halves, B), block 256 = 64 nodes x 4 groups.
// ---------------------------------------------------------------------------
__global__ __launch_bounds__(256) void k_gconv(const float* __restrict__ xT,
                                               const float* __restrict__ cw,
                                               const float* __restrict__ cb,
                                               float* __restrict__ out) {
  __shared__ float xs[Cc][64];  // 64 KiB
  const int b = blockIdx.z, n0 = blockIdx.x * 64, oh = blockIdx.y;
  const int t = threadIdx.x;
  const int lo = t & 63, hi = t >> 6;
#pragma unroll 4
  for (int r = 0; r < 64; ++r) {
    int c = hi + 4 * r;
    xs[c][lo] = xT[((b * Cc + c) * Nn) + n0 + lo];
  }
  __syncthreads();
  const int g = hi, nl = lo;
  float xv[64];
#pragma unroll
  for (int ci = 0; ci < 64; ++ci) xv[ci] = xs[g * 64 + ci][nl];
  const int obase = oh * 32;
  for (int oi = 0; oi < 32; ++oi) {
    const int co = g * 64 + obase + oi;
    float acc = cb[co];
    const float4* w4 = (const float4*)&cw[co * 64];
#pragma unroll
    for (int c4 = 0; c4 < 16; ++c4) {
      float4 w = w4[c4];
      acc = fmaf(w.x, xv[c4 * 4 + 0], acc);
      acc = fmaf(w.y, xv[c4 * 4 + 1], acc);
      acc = fmaf(w.z, xv[c4 * 4 + 2], acc);
      acc = fmaf(w.w, xv[c4 * 4 + 3], acc);
    }
    out[((b * Cc + co) * Nn) + n0 + nl] = fmaxf(acc, 0.f);
  }
}

// ---------------------------------------------------------------------------
// Fused attention apply. For block (b, h, i-tile of 128):
//   acc[i,d] = sum_j sigmoid(qt[j]+kt[i]) * roi[i,j] * sm[j] * g[b,h*64+d,j]
// MODE 0: out[b,h*64+d,i] = g[b,h*64+d,i]*(1+0.25*f_i) + 0.25*acc   ([B,C,N])
// MODE 1: out[b,i,h*64+d] = 0.25*(acc + f_i*g[b,h*64+d,i])          ([B,N,C])
// f_i = (sm[b,i]==0).  grid (N/128, H, B) = 256 blocks, block 256.
// ---------------------------------------------------------------------------
template <int MODE>
__global__ __launch_bounds__(256) void k_apply(const float* __restrict__ g,
                                               const float* __restrict__ qt,
                                               const float* __restrict__ kt,
                                               const float* __restrict__ roi,
                                               const float* __restrict__ sm,
                                               float* __restrict__ out) {
  __shared__ __align__(16) float At[64][136];  // At[j][i_local], i_local < 128
  __shared__ __align__(16) float Bt[64][68];   // Bt[j][d], d < 64
  __shared__ float kts[128];
  const int b = blockIdx.z, h = blockIdx.y, i0 = blockIdx.x * 128;
  const int t = threadIdx.x;
  const int jl = t & 63, ir = t >> 6;  // staging roles
  const int ti = t & 15, td = t >> 4;  // fma roles: i=ti*8+mi, d=td*4+md
  if (t < 128) kts[t] = kt[(b * Hh + h) * Nn + i0 + t];
  __syncthreads();

  const float* qrow = &qt[(b * Hh + h) * Nn];
  const float* smrow = &sm[b * Nn];
  float acc[8][4] = {};

  for (int j0 = 0; j0 < Nn; j0 += 64) {
    const float qv = qrow[j0 + jl];
    const float smv = smrow[j0 + jl];
    // stage Bt[j][d] = g[b, h*64+d, j0+j]
    float bvv[16];
#pragma unroll
    for (int r = 0; r < 16; ++r)
      bvv[r] = g[((b * Cc + h * 64 + ir * 16 + r) * Nn) + j0 + jl];
#pragma unroll
    for (int r4 = 0; r4 < 4; ++r4)
      *(float4*)&Bt[jl][ir * 16 + r4 * 4] =
          make_float4(bvv[r4 * 4], bvv[r4 * 4 + 1], bvv[r4 * 4 + 2], bvv[r4 * 4 + 3]);
    // stage At[j][il] = sigmoid(qt[j]+kt[i]) * roi[i,j] * sm[j]
    float av[32];
#pragma unroll
    for (int r = 0; r < 32; ++r) {
      const int il = ir * 32 + r;
      const float rv = roi[((b * Nn + i0 + il) * (long)Nn) + j0 + jl];
      const float x = qv + kts[il];
      av[r] = rv * smv * __builtin_amdgcn_rcpf(1.f + __expf(-x));
    }
#pragma unroll
    for (int r4 = 0; r4 < 8; ++r4)
      *(float4*)&At[jl][ir * 32 + r4 * 4] =
          make_float4(av[r4 * 4], av[r4 * 4 + 1], av[r4 * 4 + 2], av[r4 * 4 + 3]);
    __syncthreads();
#pragma unroll 2
    for (int j = 0; j < 64; ++j) {
      float4 a0 = *(const float4*)&At[j][ti * 8];
      float4 a1 = *(const float4*)&At[j][ti * 8 + 4];
      float4 bb = *(const float4*)&Bt[j][td * 4];
      float ai[8] = {a0.x, a0.y, a0.z, a0.w, a1.x, a1.y, a1.z, a1.w};
#pragma unroll
      for (int mi = 0; mi < 8; ++mi) {
        acc[mi][0] = fmaf(ai[mi], bb.x, acc[mi][0]);
        acc[mi][1] = fmaf(ai[mi], bb.y, acc[mi][1]);
        acc[mi][2] = fmaf(ai[mi], bb.z, acc[mi][2]);
        acc[mi][3] = fmaf(ai[mi], bb.w, acc[mi][3]);
      }
    }
    __syncthreads();
  }

  const int iBase = i0 + ti * 8;
  if (MODE == 0) {
    float fv[8];
#pragma unroll
    for (int mi = 0; mi < 8; ++mi)
      fv[mi] = (smrow[iBase + mi] == 0.f) ? 0.25f : 0.f;
#pragma unroll
    for (int md = 0; md < 4; ++md) {
      const int d = td * 4 + md;
      const float* gp = &g[((b * Cc + h * 64 + d) * Nn) + iBase];
      float* op = &out[((b * Cc + h * 64 + d) * Nn) + iBase];
      float4 g0 = *(const float4*)gp;
      float4 g1 = *(const float4*)(gp + 4);
      float4 r0, r1;
      r0.x = g0.x * (1.f + fv[0]) + 0.25f * acc[0][md];
      r0.y = g0.y * (1.f + fv[1]) + 0.25f * acc[1][md];
      r0.z = g0.z * (1.f + fv[2]) + 0.25f * acc[2][md];
      r0.w = g0.w * (1.f + fv[3]) + 0.25f * acc[3][md];
      r1.x = g1.x * (1.f + fv[4]) + 0.25f * acc[4][md];
      r1.y = g1.y * (1.f + fv[5]) + 0.25f * acc[5][md];
      r1.z = g1.z * (1.f + fv[6]) + 0.25f * acc[6][md];
      r1.w = g1.w * (1.f + fv[7]) + 0.25f * acc[7][md];
      *(float4*)op = r0;
      *(float4*)(op + 4) = r1;
    }
  } else {
#pragma unroll
    for (int mi = 0; mi < 8; ++mi) {
      const int i = iBase + mi;
      const float fvv = (smrow[i] == 0.f) ? 1.f : 0.f;
      const int dbase = h * 64 + td * 4;
      float4 r;
      r.x = 0.25f * (acc[mi][0] + fvv * g[((b * Cc + dbase + 0) * Nn) + i]);
      r.y = 0.25f * (acc[mi][1] + fvv * g[((b * Cc + dbase + 1) * Nn) + i]);
      r.z = 0.25f * (acc[mi][2] + fvv * g[((b * Cc + dbase + 2) * Nn) + i]);
      r.w = 0.25f * (acc[mi][3] + fvv * g[((b * Cc + dbase + 3) * Nn) + i]);
      *(float4*)&out[((size_t)b * Nn + i) * Cc + dbase] = r;
    }
  }
}

// ---------------------------------------------------------------------------
// LayerNorm stats over channel dim of x [B,N,C]. One wave per node.
// ---------------------------------------------------------------------------
__global__ __launch_bounds__(256) void k_lnstats(const float* __restrict__ x,
                                                 float* __restrict__ mu,
                                                 float* __restrict__ rstd) {
  const int node = blockIdx.x * 4 + (threadIdx.x >> 6);
  const int l = threadIdx.x & 63;
  float4 v = *(const float4*)&x[node * Cc + l * 4];
  float s = v.x + v.y + v.z + v.w;
  float sq = v.x * v.x + v.y * v.y + v.z * v.z + v.w * v.w;
#pragma unroll
  for (int off = 32; off; off >>= 1) {
    s += __shfl_xor(s, off, 64);
    sq += __shfl_xor(sq, off, 64);
  }
  if (l == 0) {
    float m = s * (1.f / 256.f);
    float var = sq * (1.f / 256.f) - m * m;
    mu[node] = m;
    rstd[node] = rsqrtf(fmaxf(var, 0.f) + 1e-6f);
  }
}

// ---------------------------------------------------------------------------
// Final: io [B,N,C] (holds outm2T) updated in place:
//   y[b,i,c] = g2[b,c,i] + (io[b,i,c]-mu)*rstd*lng[c] + lnb[c]
// grid (N/64, C/64, B), block 256.
// ---------------------------------------------------------------------------
__global__ __launch_bounds__(256) void k_final(float* __restrict__ io,
                                               const float* __restrict__ g2,
                                               const float* __restrict__ mu,
                                               const float* __restrict__ rstd,
                                               const float* __restrict__ lng,
                                               const float* __restrict__ lnb) {
  __shared__ float gt[64][65];
  const int b = blockIdx.z, i0 = blockIdx.x * 64, c0 = blockIdx.y * 64;
  const int t = threadIdx.x;
  const int lo = t & 63, hi = t >> 6;
#pragma unroll
  for (int r = 0; r < 16; ++r) {
    int cl = hi + 4 * r;
    gt[cl][lo] = g2[((b * Cc + c0 + cl) * Nn) + i0 + lo];
  }
  __syncthreads();
#pragma unroll
  for (int r = 0; r < 16; ++r) {
    int il = hi + 4 * r;
    int node = b * Nn + i0 + il;
    int idx = node * Cc + c0 + lo;
    float v = io[idx];
    io[idx] = gt[lo][il] + (v - mu[node]) * rstd[node] * lng[c0 + lo] + lnb[c0 + lo];
  }
}

// ---------------------------------------------------------------------------
extern "C" void kernel_launch(void* const* d_in, const int* in_sizes, int n_in,
                              void* d_out, int out_size, void* d_ws, size_t ws_size,
                              hipStream_t stream) {
  (void)in_sizes; (void)n_in; (void)out_size; (void)ws_size;
  const float* input = (const float*)d_in[0];
  const float* roi   = (const float*)d_in[1];   // masks_roi [B,N,N]
  const float* sm    = (const float*)d_in[2];   // score_mask [B,N]
  const float* spat  = (const float*)d_in[3];
  const float* W1    = (const float*)d_in[4];
  const float* b1    = (const float*)d_in[5];
  const float* W2    = (const float*)d_in[6];
  const float* b2    = (const float*)d_in[7];
  const float* cw1   = (const float*)d_in[8];
  const float* cb1   = (const float*)d_in[9];
  const float* cw2   = (const float*)d_in[10];
  const float* cb2   = (const float*)d_in[11];
  const float* lng   = (const float*)d_in[12];
  const float* lnb   = (const float*)d_in[13];
  // d_in[14] = node_num: unused — scores[b,i,i]=1 is the strict row max, so
  // every column lands in some row's top-k and the `present` mask is all-ones.

  float* outf = (float*)d_out;
  float* ws = (float*)d_ws;
  const size_t PLANE = (size_t)Bb * Cc * Nn;  // 2M floats
  float* gbuf = ws;                 // conv output (g1 then g2)
  float* out1 = ws + PLANE;         // stage-1 result [B,C,N]
  float* qtb  = ws + 2 * PLANE;     // [B,H,N]
  float* ktb  = qtb + Bb * Hh * Nn; // [B,H,N]
  float* mub  = ktb + Bb * Hh * Nn; // [B,N]
  float* rsb  = mub + Bb * Nn;      // [B,N]
  float* inT  = outf;               // d_out doubles as scratch for x^T early on

  k_transpose<<<dim3(16, 4, 8), 256, 0, stream>>>(input, inT);
  k_qkt<<<dim3(16, 8), 256, 0, stream>>>(inT, spat, W1, b1, qtb, ktb);
  k_gconv<<<dim3(16, 2, 8), 256, 0, stream>>>(inT, cw1, cb1, gbuf);
  k_apply<0><<<dim3(8, 4, 8), 256, 0, stream>>>(gbuf, qtb, ktb, roi, sm, out1);
  k_qkt<<<dim3(16, 8), 256, 0, stream>>>(out1, spat, W2, b2, qtb, ktb);
  k_gconv<<<dim3(16, 2, 8), 256, 0, stream>>>(out1, cw2, cb2, gbuf);
  k_apply<1><<<dim3(8, 4, 8), 256, 0, stream>>>(gbuf, qtb, ktb, roi, sm, outf);
  k_lnstats<<<dim3(2048), 256, 0, stream>>>(outf, mub, rsb);
  k_final<<<dim3(16, 4, 8), 256, 0, stream>>>(outf, gbuf, mub, rsb, lng, lnb);
}

// Round 2
// 166.462 us; speedup vs baseline: 1.7860x; 1.7860x over previous
//
#include <hip/hip_runtime.h>

constexpr int Bb = 8;     // batch
constexpr int Nn = 1024;  // nodes
constexpr int Cc = 256;   // channels
constexpr int Hh = 4;     // heads

typedef float fx4 __attribute__((ext_vector_type(4)));
typedef float f32x4 __attribute__((ext_vector_type(4)));
typedef __bf16 bf16x8 __attribute__((ext_vector_type(8)));

// ---------------------------------------------------------------------------
// Transpose [B,N,C] -> [B,C,N]. grid (N/64, C/64, B), block 256.
// ---------------------------------------------------------------------------
__global__ __launch_bounds__(256) void k_transpose(const float* __restrict__ in,
                                                   float* __restrict__ out) {
  __shared__ float tile[64][65];
  const int b = blockIdx.z, n0 = blockIdx.x * 64, c0 = blockIdx.y * 64;
  const int t = threadIdx.x;
  const int lo = t & 63, hi = t >> 6;
#pragma unroll
  for (int r = 0; r < 16; ++r) {
    int nl = hi + 4 * r;
    tile[nl][lo] = in[((b * Nn + n0 + nl) * Cc) + c0 + lo];
  }
  __syncthreads();
#pragma unroll
  for (int r = 0; r < 16; ++r) {
    int cl = hi + 4 * r;
    out[((b * Cc + c0 + cl) * Nn) + n0 + lo] = tile[lo][cl];
  }
}

// ---------------------------------------------------------------------------
// qt/kt projection. xT is [B,C,N]. W is [H, 2C+4] = [Wq | Wk | Wsq | Wsk].
// grid (N/64, B), block 256 = 64 nodes x 4 heads.
// ---------------------------------------------------------------------------
__global__ __launch_bounds__(256) void k_qkt(const float* __restrict__ xT,
                                             const float* __restrict__ spat,
                                             const float* __restrict__ W,
                                             const float* __restrict__ bias,
                                             float* __restrict__ qt,
                                             float* __restrict__ kt) {
  __shared__ float Ws[4 * 516];
  const int b = blockIdx.y, n0 = blockIdx.x * 64;
  const int t = threadIdx.x;
  for (int idx = t; idx < 4 * 516; idx += 256) Ws[idx] = W[idx];
  __syncthreads();
  const int h = t >> 6, nl = t & 63, n = n0 + nl;
  const float* wq = &Ws[h * 516];
  const float* wk = wq + Cc;
  float qa = 0.f, ka = 0.f;
#pragma unroll 8
  for (int c = 0; c < Cc; ++c) {
    float xv = xT[((b * Cc + c) * Nn) + n];
    qa = fmaf(xv, wq[c], qa);
    ka = fmaf(xv, wk[c], ka);
  }
  const float s0 = spat[(b * Nn + n) * 2 + 0];
  const float s1 = spat[(b * Nn + n) * 2 + 1];
  qa += s0 * wq[2 * Cc + 0] + s1 * wq[2 * Cc + 1];  // Wsq
  ka += s0 * wq[2 * Cc + 2] + s1 * wq[2 * Cc + 3];  // Wsk
  qt[(b * Hh + h) * Nn + n] = qa + bias[h];         // fold logit bias into qt
  kt[(b * Hh + h) * Nn + n] = ka;
}

// ---------------------------------------------------------------------------
// Grouped 1x1 conv + ReLU. xT [B,C,N] -> out [B,C,N]. cw [G=4][64][64].
// grid (N/64, 2 o-halves, B), block 256 = 64 nodes x 4 groups.
// ---------------------------------------------------------------------------
__global__ __launch_bounds__(256) void k_gconv(const float* __restrict__ xT,
                                               const float* __restrict__ cw,
                                               const float* __restrict__ cb,
                                               float* __restrict__ out) {
  __shared__ float xs[Cc][64];  // 64 KiB
  const int b = blockIdx.z, n0 = blockIdx.x * 64, oh = blockIdx.y;
  const int t = threadIdx.x;
  const int lo = t & 63, hi = t >> 6;
#pragma unroll 4
  for (int r = 0; r < 64; ++r) {
    int c = hi + 4 * r;
    xs[c][lo] = xT[((b * Cc + c) * Nn) + n0 + lo];
  }
  __syncthreads();
  const int g = hi, nl = lo;
  float xv[64];
#pragma unroll
  for (int ci = 0; ci < 64; ++ci) xv[ci] = xs[g * 64 + ci][nl];
  const int obase = oh * 32;
  for (int oi = 0; oi < 32; ++oi) {
    const int co = g * 64 + obase + oi;
    float acc = cb[co];
    const float4* w4 = (const float4*)&cw[co * 64];
#pragma unroll
    for (int c4 = 0; c4 < 16; ++c4) {
      float4 w = w4[c4];
      acc = fmaf(w.x, xv[c4 * 4 + 0], acc);
      acc = fmaf(w.y, xv[c4 * 4 + 1], acc);
      acc = fmaf(w.z, xv[c4 * 4 + 2], acc);
      acc = fmaf(w.w, xv[c4 * 4 + 3], acc);
    }
    out[((b * Cc + co) * Nn) + n0 + nl] = fmaxf(acc, 0.f);
  }
}

// ---------------------------------------------------------------------------
// MFMA fused attention apply.
// Per block (b, it, h): C[i,d] = sum_j sig(qt[j]+kt[i]) * roi[i,j] * sm[j] * G[d,j]
// for i in [it*64, it*64+64), d in [0,64) of head h's channels.
// Wave w owns i-subtile of 16. A-fragment built in registers from roi+sigmoid
// (lane&15 = i-row, 8 consecutive j per lane = contiguous roi). B = sm[j]*G[d,j]
// staged bf16 in LDS (shared by 4 waves), double-buffered, pad stride 40.
// MODE 0: out[b,ch,i] = g[b,ch,i]*(1+0.25*f_i) + 0.25*C   ([B,C,N])
// MODE 1: out[b,i,ch] = 0.25*(C + f_i*g[b,ch,i])          ([B,N,C])
// grid dim3(8 b, 16 it, 4 h) => linear%8 == b => each XCD serves one batch,
// so roi[b] (4MB) lives in that XCD's private L2 across all 64 blocks.
// ---------------------------------------------------------------------------
template <int MODE>
__global__ __launch_bounds__(256) void k_apply_mfma(const float* __restrict__ g,
                                                    const float* __restrict__ qt,
                                                    const float* __restrict__ kt,
                                                    const float* __restrict__ roi,
                                                    const float* __restrict__ sm,
                                                    float* __restrict__ out) {
  __shared__ __align__(16) __bf16 Bs[2][64 * 40];  // 10.25 KB total
  const int b = blockIdx.x, it = blockIdx.y, h = blockIdx.z;
  const int t = threadIdx.x, w = t >> 6, l = t & 63;
  const int i0 = it * 64;
  const int dl = l & 15;          // B/D fragment column (d within 16-frag)
  const int jq = (l >> 4) * 8;    // k-offset of this lane's 8 elements
  const int iA = i0 + w * 16 + dl;  // A fragment row for this lane

  const float kv = kt[(b * Hh + h) * Nn + iA];
  const float* qrow = qt + (b * Hh + h) * Nn;
  const float* rrow = roi + ((size_t)(b * Nn + iA)) * Nn;
  const float* smrow = sm + b * Nn;

  // staging role: thread t stages 8 j for channel d = t>>2
  const int sd = t >> 2, sjj = (t & 3) * 8;
  const float* gs = g + ((size_t)(b * Cc + h * 64 + sd)) * Nn;

  f32x4 acc[4] = {};

  // ---- prologue: prefetch step-0 A inputs, stage Bs[0] ----
  fx4 rA = *(const fx4*)&rrow[jq];
  fx4 rB = *(const fx4*)&rrow[jq + 4];
  fx4 qA = *(const fx4*)&qrow[jq];
  fx4 qB = *(const fx4*)&qrow[jq + 4];
  {
    fx4 gA = *(const fx4*)&gs[sjj];
    fx4 gB = *(const fx4*)&gs[sjj + 4];
    fx4 sA = *(const fx4*)&smrow[sjj];
    fx4 sB = *(const fx4*)&smrow[sjj + 4];
    bf16x8 bsv;
#pragma unroll
    for (int e = 0; e < 4; ++e) bsv[e] = (__bf16)(gA[e] * sA[e]);
#pragma unroll
    for (int e = 0; e < 4; ++e) bsv[4 + e] = (__bf16)(gB[e] * sB[e]);
    *(bf16x8*)&Bs[0][sd * 40 + sjj] = bsv;
  }
  __syncthreads();

  // ---- main loop: 32 K-steps of 32 ----
  for (int s = 0; s < 32; ++s) {
    const int cur = s & 1;
    fx4 rA2, rB2, qA2, qB2, gA2, gB2, sA2, sB2;
    if (s < 31) {
      const int j0n = (s + 1) * 32;
      rA2 = *(const fx4*)&rrow[j0n + jq];
      rB2 = *(const fx4*)&rrow[j0n + jq + 4];
      qA2 = *(const fx4*)&qrow[j0n + jq];
      qB2 = *(const fx4*)&qrow[j0n + jq + 4];
      gA2 = *(const fx4*)&gs[j0n + sjj];
      gB2 = *(const fx4*)&gs[j0n + sjj + 4];
      sA2 = *(const fx4*)&smrow[j0n + sjj];
      sB2 = *(const fx4*)&smrow[j0n + sjj + 4];
    }
    // A-fragment: sigmoid(qt[j]+kt[i]) * roi[i,j], 8 j per lane, in registers
    bf16x8 af;
#pragma unroll
    for (int e = 0; e < 4; ++e) {
      float x = qA[e] + kv;
      float sg = __builtin_amdgcn_rcpf(1.f + __builtin_amdgcn_exp2f(x * -1.44269504f));
      af[e] = (__bf16)(sg * rA[e]);
    }
#pragma unroll
    for (int e = 0; e < 4; ++e) {
      float x = qB[e] + kv;
      float sg = __builtin_amdgcn_rcpf(1.f + __builtin_amdgcn_exp2f(x * -1.44269504f));
      af[4 + e] = (__bf16)(sg * rB[e]);
    }
    // 4 d-fragments x MFMA
#pragma unroll
    for (int nf = 0; nf < 4; ++nf) {
      bf16x8 bf = *(const bf16x8*)&Bs[cur][(nf * 16 + dl) * 40 + jq];
      acc[nf] = __builtin_amdgcn_mfma_f32_16x16x32_bf16(af, bf, acc[nf], 0, 0, 0);
    }
    // stage next B tile (after compute: global latency hidden under MFMA/VALU)
    if (s < 31) {
      bf16x8 bsv;
#pragma unroll
      for (int e = 0; e < 4; ++e) bsv[e] = (__bf16)(gA2[e] * sA2[e]);
#pragma unroll
      for (int e = 0; e < 4; ++e) bsv[4 + e] = (__bf16)(gB2[e] * sB2[e]);
      *(bf16x8*)&Bs[cur ^ 1][sd * 40 + sjj] = bsv;
      rA = rA2; rB = rB2; qA = qA2; qB = qB2;
    }
    __syncthreads();
  }

  // ---- epilogue ----
  // D layout: col(d) = lane&15, row(i) = (lane>>4)*4 + reg
  const int rowg = l >> 4;
  const int iw = i0 + w * 16 + rowg * 4;
  fx4 sv = *(const fx4*)&smrow[iw];
  if (MODE == 0) {
    float fv[4];
#pragma unroll
    for (int r = 0; r < 4; ++r) fv[r] = (sv[r] == 0.f) ? 0.25f : 0.f;
#pragma unroll
    for (int nf = 0; nf < 4; ++nf) {
      const int ch = h * 64 + nf * 16 + dl;
      const size_t base = ((size_t)(b * Cc + ch)) * Nn + iw;
      fx4 gv = *(const fx4*)&g[base];
      fx4 res;
#pragma unroll
      for (int r = 0; r < 4; ++r) res[r] = gv[r] * (1.f + fv[r]) + 0.25f * acc[nf][r];
      *(fx4*)&out[base] = res;
    }
  } else {
    float fv[4];
#pragma unroll
    for (int r = 0; r < 4; ++r) fv[r] = (sv[r] == 0.f) ? 1.f : 0.f;
#pragma unroll
    for (int nf = 0; nf < 4; ++nf) {
      const int ch = h * 64 + nf * 16 + dl;
      fx4 gv = *(const fx4*)&g[((size_t)(b * Cc + ch)) * Nn + iw];
#pragma unroll
      for (int r = 0; r < 4; ++r)
        out[((size_t)b * Nn + iw + r) * Cc + ch] = 0.25f * (acc[nf][r] + fv[r] * gv[r]);
    }
  }
}

// ---------------------------------------------------------------------------
// LayerNorm stats over channel dim of x [B,N,C]. One wave per node.
// ---------------------------------------------------------------------------
__global__ __launch_bounds__(256) void k_lnstats(const float* __restrict__ x,
                                                 float* __restrict__ mu,
                                                 float* __restrict__ rstd) {
  const int node = blockIdx.x * 4 + (threadIdx.x >> 6);
  const int l = threadIdx.x & 63;
  float4 v = *(const float4*)&x[node * Cc + l * 4];
  float s = v.x + v.y + v.z + v.w;
  float sq = v.x * v.x + v.y * v.y + v.z * v.z + v.w * v.w;
#pragma unroll
  for (int off = 32; off; off >>= 1) {
    s += __shfl_xor(s, off, 64);
    sq += __shfl_xor(sq, off, 64);
  }
  if (l == 0) {
    float m = s * (1.f / 256.f);
    float var = sq * (1.f / 256.f) - m * m;
    mu[node] = m;
    rstd[node] = rsqrtf(fmaxf(var, 0.f) + 1e-6f);
  }
}

// ---------------------------------------------------------------------------
// Final: io [B,N,C] (holds outm2T) updated in place:
//   y[b,i,c] = g2[b,c,i] + (io[b,i,c]-mu)*rstd*lng[c] + lnb[c]
// ---------------------------------------------------------------------------
__global__ __launch_bounds__(256) void k_final(float* __restrict__ io,
                                               const float* __restrict__ g2,
                                               const float* __restrict__ mu,
                                               const float* __restrict__ rstd,
                                               const float* __restrict__ lng,
                                               const float* __restrict__ lnb) {
  __shared__ float gt[64][65];
  const int b = blockIdx.z, i0 = blockIdx.x * 64, c0 = blockIdx.y * 64;
  const int t = threadIdx.x;
  const int lo = t & 63, hi = t >> 6;
#pragma unroll
  for (int r = 0; r < 16; ++r) {
    int cl = hi + 4 * r;
    gt[cl][lo] = g2[((b * Cc + c0 + cl) * Nn) + i0 + lo];
  }
  __syncthreads();
#pragma unroll
  for (int r = 0; r < 16; ++r) {
    int il = hi + 4 * r;
    int node = b * Nn + i0 + il;
    int idx = node * Cc + c0 + lo;
    float v = io[idx];
    io[idx] = gt[lo][il] + (v - mu[node]) * rstd[node] * lng[c0 + lo] + lnb[c0 + lo];
  }
}

// ---------------------------------------------------------------------------
extern "C" void kernel_launch(void* const* d_in, const int* in_sizes, int n_in,
                              void* d_out, int out_size, void* d_ws, size_t ws_size,
                              hipStream_t stream) {
  (void)in_sizes; (void)n_in; (void)out_size; (void)ws_size;
  const float* input = (const float*)d_in[0];
  const float* roi   = (const float*)d_in[1];   // masks_roi [B,N,N]
  const float* sm    = (const float*)d_in[2];   // score_mask [B,N]
  const float* spat  = (const float*)d_in[3];
  const float* W1    = (const float*)d_in[4];
  const float* b1    = (const float*)d_in[5];
  const float* W2    = (const float*)d_in[6];
  const float* b2    = (const float*)d_in[7];
  const float* cw1   = (const float*)d_in[8];
  const float* cb1   = (const float*)d_in[9];
  const float* cw2   = (const float*)d_in[10];
  const float* cb2   = (const float*)d_in[11];
  const float* lng   = (const float*)d_in[12];
  const float* lnb   = (const float*)d_in[13];
  // d_in[14] = node_num: unused — scores[b,i,i]=1 is the strict row max, so
  // every column lands in some row's top-k and the `present` mask is all-ones.

  float* outf = (float*)d_out;
  float* ws = (float*)d_ws;
  const size_t PLANE = (size_t)Bb * Cc * Nn;  // 2M floats
  float* gbuf = ws;                 // conv output (g1 then g2)
  float* out1 = ws + PLANE;         // stage-1 result [B,C,N]
  float* qtb  = ws + 2 * PLANE;     // [B,H,N]
  float* ktb  = qtb + Bb * Hh * Nn; // [B,H,N]
  float* mub  = ktb + Bb * Hh * Nn; // [B,N]
  float* rsb  = mub + Bb * Nn;      // [B,N]
  float* inT  = outf;               // d_out doubles as scratch for x^T early on

  k_transpose<<<dim3(16, 4, 8), 256, 0, stream>>>(input, inT);
  k_qkt<<<dim3(16, 8), 256, 0, stream>>>(inT, spat, W1, b1, qtb, ktb);
  k_gconv<<<dim3(16, 2, 8), 256, 0, stream>>>(inT, cw1, cb1, gbuf);
  k_apply_mfma<0><<<dim3(8, 16, 4), 256, 0, stream>>>(gbuf, qtb, ktb, roi, sm, out1);
  k_qkt<<<dim3(16, 8), 256, 0, stream>>>(out1, spat, W2, b2, qtb, ktb);
  k_gconv<<<dim3(16, 2, 8), 256, 0, stream>>>(out1, cw2, cb2, gbuf);
  k_apply_mfma<1><<<dim3(8, 16, 4), 256, 0, stream>>>(gbuf, qtb, ktb, roi, sm, outf);
  k_lnstats<<<dim3(2048), 256, 0, stream>>>(outf, mub, rsb);
  k_final<<<dim3(16, 4, 8), 256, 0, stream>>>(outf, gbuf, mub, rsb, lng, lnb);
}

// Round 5
// 143.689 us; speedup vs baseline: 2.0690x; 1.1585x over previous
//
#include <hip/hip_runtime.h>

constexpr int Bb = 8;     // batch
constexpr int Nn = 1024;  // nodes
constexpr int Cc = 256;   // channels
constexpr int Hh = 4;     // heads
constexpr int WROW = 2 * Cc + 4;  // 516, same for W1 and W2

typedef float fx4 __attribute__((ext_vector_type(4)));
typedef float f32x4 __attribute__((ext_vector_type(4)));
typedef __bf16 bf16x8 __attribute__((ext_vector_type(8)));

// ---------------------------------------------------------------------------
// Pack (roi[b,i,j]!=0 && sm[b,j]!=0) into bits. roib: [B*N][16] u64 (128B/row).
// One wave per row, 16 ballots of 64 j each. grid 2048, block 256.
// ---------------------------------------------------------------------------
__global__ __launch_bounds__(256) void k_roipack(const float* __restrict__ roi,
                                                 const float* __restrict__ sm,
                                                 unsigned long long* __restrict__ roib) {
  const int gid = blockIdx.x * 4 + (threadIdx.x >> 6);  // row over B*N
  const int b = gid >> 10;
  const int l = threadIdx.x & 63;
  const float* rrow = roi + (size_t)gid * Nn;
  const float* smrow = sm + b * Nn;
  unsigned long long* orow = roib + (size_t)gid * 16;
#pragma unroll 4
  for (int jc = 0; jc < 16; ++jc) {
    float rv = rrow[jc * 64 + l];
    float sv = smrow[jc * 64 + l];
    unsigned long long m = __ballot(rv != 0.f && sv != 0.f);
    if (l == 0) orow[jc] = m;
  }
}

// ---------------------------------------------------------------------------
// Transpose [B,N,C] -> [B,C,N]. grid (N/64, C/64, B), block 256.
// ---------------------------------------------------------------------------
__global__ __launch_bounds__(256) void k_transpose(const float* __restrict__ in,
                                                   float* __restrict__ out) {
  __shared__ float tile[64][65];
  const int b = blockIdx.z, n0 = blockIdx.x * 64, c0 = blockIdx.y * 64;
  const int t = threadIdx.x;
  const int lo = t & 63, hi = t >> 6;
#pragma unroll
  for (int r = 0; r < 16; ++r) {
    int nl = hi + 4 * r;
    tile[nl][lo] = in[((b * Nn + n0 + nl) * Cc) + c0 + lo];
  }
  __syncthreads();
#pragma unroll
  for (int r = 0; r < 16; ++r) {
    int cl = hi + 4 * r;
    out[((b * Cc + c0 + cl) * Nn) + n0 + lo] = tile[lo][cl];
  }
}

// ---------------------------------------------------------------------------
// Grouped 1x1 conv + ReLU + fused qt/kt projection.
// xT [B,C,N] -> out f32 [B,C,N], gsm bf16 (= 0.25*sm*relu).
// qkt: oh==0 blocks compute qt (Wq,Wsq,+bias), oh==1 blocks compute kt.
// W rows are [Wq(C) | Wk(C) | Wsq(2) | Wsk(2)], row stride 516.
// grid (N/64, 2, B), block 256 = 64 nodes x 4 (groups == heads).
// ---------------------------------------------------------------------------
__global__ __launch_bounds__(256) void k_gconvq(const float* __restrict__ xT,
                                                const float* __restrict__ cw,
                                                const float* __restrict__ cb,
                                                const float* __restrict__ sm,
                                                const float* __restrict__ spat,
                                                const float* __restrict__ W,
                                                const float* __restrict__ bias,
                                                float* __restrict__ out,
                                                __bf16* __restrict__ gsm,
                                                float* __restrict__ qt,
                                                float* __restrict__ kt) {
  __shared__ float xs[Cc][64];  // 64 KiB
  const int b = blockIdx.z, n0 = blockIdx.x * 64, oh = blockIdx.y;
  const int t = threadIdx.x;
  const int lo = t & 63, hi = t >> 6;
#pragma unroll 4
  for (int r = 0; r < 64; ++r) {
    int c = hi + 4 * r;
    xs[c][lo] = xT[((b * Cc + c) * Nn) + n0 + lo];
  }
  __syncthreads();
  const int g = hi, nl = lo, n = n0 + nl;

  // ---- qt/kt projection from the staged tile (oh picks q vs k) ----
  {
    const int h = hi;
    const float* wrow = W + h * WROW + oh * Cc;  // Wq or Wk
    float a = 0.f;
#pragma unroll 8
    for (int c = 0; c < Cc; ++c) a = fmaf(xs[c][nl], wrow[c], a);
    const float s0 = spat[(b * Nn + n) * 2 + 0];
    const float s1 = spat[(b * Nn + n) * 2 + 1];
    const float* wsp = W + h * WROW + 2 * Cc + oh * 2;  // Wsq or Wsk
    a += s0 * wsp[0] + s1 * wsp[1];
    if (oh == 0)
      qt[(b * Hh + h) * Nn + n] = a + bias[h];  // fold logit bias into qt
    else
      kt[(b * Hh + h) * Nn + n] = a;
  }

  // ---- grouped conv ----
  const float smv = 0.25f * sm[b * Nn + n];
  float xv[64];
#pragma unroll
  for (int ci = 0; ci < 64; ++ci) xv[ci] = xs[g * 64 + ci][nl];
  const int obase = oh * 32;
  for (int oi = 0; oi < 32; ++oi) {
    const int co = g * 64 + obase + oi;
    float acc = cb[co];
    const float4* w4 = (const float4*)&cw[co * 64];
#pragma unroll
    for (int c4 = 0; c4 < 16; ++c4) {
      float4 w = w4[c4];
      acc = fmaf(w.x, xv[c4 * 4 + 0], acc);
      acc = fmaf(w.y, xv[c4 * 4 + 1], acc);
      acc = fmaf(w.z, xv[c4 * 4 + 2], acc);
      acc = fmaf(w.w, xv[c4 * 4 + 3], acc);
    }
    const float relu = fmaxf(acc, 0.f);
    const size_t idx = ((size_t)(b * Cc + co)) * Nn + n0 + nl;
    out[idx] = relu;
    gsm[idx] = (__bf16)(smv * relu);
  }
}

// ---------------------------------------------------------------------------
// MFMA fused attention apply (= proven v2 skeleton + roib + gsm inputs).
// Per block (b, it, h): C[i,d] = 0.25*sum_j sig(qt[j]+kt[i])*mask[i,j]*G[d,j]
// A-fragment built in registers: lane (w,dl) owns row i = i0+w*16+dl, its 8
// contiguous j come from one roib byte + sigmoid. B = gsm (pre-scaled bf16),
// reg-staged into pad-40 LDS, double-buffered, one __syncthreads per K-step.
// MODE 0: out[b,ch,i] = g[b,ch,i]*(1+fv) + C      ([B,C,N]), fv=0.25*f_i
// MODE 1: out[b,i,ch] = C + fv*g[b,ch,i]          ([B,N,C])
// grid dim3(8 b, 16 it, 4 h): linear%8 == b -> each XCD serves one batch.
// ---------------------------------------------------------------------------
template <int MODE>
__global__ __launch_bounds__(256) void k_apply3(const float* __restrict__ g,
                                                const __bf16* __restrict__ gsm,
                                                const float* __restrict__ qt,
                                                const float* __restrict__ kt,
                                                const unsigned char* __restrict__ roib,
                                                const float* __restrict__ sm,
                                                float* __restrict__ out) {
  __shared__ __align__(16) __bf16 Bs[2][64 * 40];  // 10.25 KB
  __shared__ __align__(16) float qts[1024];        // qt * -log2e
  const int b = blockIdx.x, it = blockIdx.y, h = blockIdx.z;
  const int t = threadIdx.x, w = t >> 6, l = t & 63;
  const int i0 = it * 64;
  const int dl = l & 15, q = l >> 4, jqf = q * 8;
  const int iA = i0 + w * 16 + dl;

  const float kvn = kt[(b * Hh + h) * Nn + iA] * -1.44269504f;
  const unsigned char* rbrow = roib + ((size_t)(b * Nn + iA)) * 128;
  const float* smrow = sm + b * Nn;

  // staging role: thread t stages 8 j for row sd = t>>2, chunk t&3
  const int sd = t >> 2, sjc = t & 3;
  const __bf16* gsrc = gsm + ((size_t)(b * Cc + h * 64 + sd)) * Nn + sjc * 8;

  // qt row staged once, pre-scaled by -log2e
  {
    const float* qtrow = qt + (b * Hh + h) * Nn;
    fx4 qv = *(const fx4*)&qtrow[t * 4];
    fx4 qn;
#pragma unroll
    for (int e = 0; e < 4; ++e) qn[e] = qv[e] * -1.44269504f;
    *(fx4*)&qts[t * 4] = qn;
  }
  // stage B tile for step 0
  *(bf16x8*)&Bs[0][sd * 40 + sjc * 8] = *(const bf16x8*)gsrc;
  unsigned int rb_cur = rbrow[q];
  __syncthreads();

  f32x4 acc[4] = {};
#pragma unroll 2
  for (int s = 0; s < 32; ++s) {
    const int cur = s & 1;
    bf16x8 bnext;
    unsigned int rb_next = 0;
    if (s < 31) {
      bnext = *(const bf16x8*)(gsrc + (s + 1) * 32);
      rb_next = rbrow[(s + 1) * 4 + q];
    }
    // A-fragment: sigmoid gated by roib bits, 8 contiguous j per lane
    fx4 qa = *(const fx4*)&qts[s * 32 + jqf];
    fx4 qb = *(const fx4*)&qts[s * 32 + jqf + 4];
    bf16x8 af;
#pragma unroll
    for (int e = 0; e < 4; ++e) {
      float p = __builtin_amdgcn_exp2f(qa[e] + kvn);
      float sg = __builtin_amdgcn_rcpf(1.f + p);
      af[e] = (__bf16)(((rb_cur >> e) & 1) ? sg : 0.f);
    }
#pragma unroll
    for (int e = 0; e < 4; ++e) {
      float p = __builtin_amdgcn_exp2f(qb[e] + kvn);
      float sg = __builtin_amdgcn_rcpf(1.f + p);
      af[4 + e] = (__bf16)(((rb_cur >> (4 + e)) & 1) ? sg : 0.f);
    }
#pragma unroll
    for (int nf = 0; nf < 4; ++nf) {
      bf16x8 bv = *(const bf16x8*)&Bs[cur][(nf * 16 + dl) * 40 + jqf];
      acc[nf] = __builtin_amdgcn_mfma_f32_16x16x32_bf16(af, bv, acc[nf], 0, 0, 0);
    }
    if (s < 31) {
      *(bf16x8*)&Bs[cur ^ 1][sd * 40 + sjc * 8] = bnext;
      rb_cur = rb_next;
    }
    __syncthreads();
  }

  // ---- epilogue: D layout col(d)=lane&15, row(i)=(lane>>4)*4+reg ----
  const int rowg = l >> 4;
  const int iw = i0 + w * 16 + rowg * 4;
  fx4 sv = *(const fx4*)&smrow[iw];
  float fv[4];
#pragma unroll
  for (int r = 0; r < 4; ++r) fv[r] = (sv[r] == 0.f) ? 0.25f : 0.f;
  if (MODE == 0) {
#pragma unroll
    for (int nf = 0; nf < 4; ++nf) {
      const int ch = h * 64 + nf * 16 + dl;
      const size_t base = ((size_t)(b * Cc + ch)) * Nn + iw;
      fx4 gv = *(const fx4*)&g[base];
      fx4 res;
#pragma unroll
      for (int r = 0; r < 4; ++r) res[r] = gv[r] * (1.f + fv[r]) + acc[nf][r];
      *(fx4*)&out[base] = res;
    }
  } else {
#pragma unroll
    for (int nf = 0; nf < 4; ++nf) {
      const int ch = h * 64 + nf * 16 + dl;
      fx4 gv = *(const fx4*)&g[((size_t)(b * Cc + ch)) * Nn + iw];
#pragma unroll
      for (int r = 0; r < 4; ++r)
        out[((size_t)b * Nn + iw + r) * Cc + ch] = acc[nf][r] + fv[r] * gv[r];
    }
  }
}

// ---------------------------------------------------------------------------
// LayerNorm stats over channel dim of x [B,N,C]. One wave per node.
// ---------------------------------------------------------------------------
__global__ __launch_bounds__(256) void k_lnstats(const float* __restrict__ x,
                                                 float* __restrict__ mu,
                                                 float* __restrict__ rstd) {
  const int node = blockIdx.x * 4 + (threadIdx.x >> 6);
  const int l = threadIdx.x & 63;
  float4 v = *(const float4*)&x[node * Cc + l * 4];
  float s = v.x + v.y + v.z + v.w;
  float sq = v.x * v.x + v.y * v.y + v.z * v.z + v.w * v.w;
#pragma unroll
  for (int off = 32; off; off >>= 1) {
    s += __shfl_xor(s, off, 64);
    sq += __shfl_xor(sq, off, 64);
  }
  if (l == 0) {
    float m = s * (1.f / 256.f);
    float var = sq * (1.f / 256.f) - m * m;
    mu[node] = m;
    rstd[node] = rsqrtf(fmaxf(var, 0.f) + 1e-6f);
  }
}

// ---------------------------------------------------------------------------
// Final: io [B,N,C] (holds outm2T) updated in place:
//   y[b,i,c] = g2[b,c,i] + (io[b,i,c]-mu)*rstd*lng[c] + lnb[c]
// ---------------------------------------------------------------------------
__global__ __launch_bounds__(256) void k_final(float* __restrict__ io,
                                               const float* __restrict__ g2,
                                               const float* __restrict__ mu,
                                               const float* __restrict__ rstd,
                                               const float* __restrict__ lng,
                                               const float* __restrict__ lnb) {
  __shared__ float gt[64][65];
  const int b = blockIdx.z, i0 = blockIdx.x * 64, c0 = blockIdx.y * 64;
  const int t = threadIdx.x;
  const int lo = t & 63, hi = t >> 6;
#pragma unroll
  for (int r = 0; r < 16; ++r) {
    int cl = hi + 4 * r;
    gt[cl][lo] = g2[((b * Cc + c0 + cl) * Nn) + i0 + lo];
  }
  __syncthreads();
#pragma unroll
  for (int r = 0; r < 16; ++r) {
    int il = hi + 4 * r;
    int node = b * Nn + i0 + il;
    int idx = node * Cc + c0 + lo;
    float v = io[idx];
    io[idx] = gt[lo][il] + (v - mu[node]) * rstd[node] * lng[c0 + lo] + lnb[c0 + lo];
  }
}

// ---------------------------------------------------------------------------
extern "C" void kernel_launch(void* const* d_in, const int* in_sizes, int n_in,
                              void* d_out, int out_size, void* d_ws, size_t ws_size,
                              hipStream_t stream) {
  (void)in_sizes; (void)n_in; (void)out_size; (void)ws_size;
  const float* input = (const float*)d_in[0];
  const float* roi   = (const float*)d_in[1];   // masks_roi [B,N,N]
  const float* sm    = (const float*)d_in[2];   // score_mask [B,N]
  const float* spat  = (const float*)d_in[3];
  const float* W1    = (const float*)d_in[4];
  const float* b1    = (const float*)d_in[5];
  const float* W2    = (const float*)d_in[6];
  const float* b2    = (const float*)d_in[7];
  const float* cw1   = (const float*)d_in[8];
  const float* cb1   = (const float*)d_in[9];
  const float* cw2   = (const float*)d_in[10];
  const float* cb2   = (const float*)d_in[11];
  const float* lng   = (const float*)d_in[12];
  const float* lnb   = (const float*)d_in[13];
  // d_in[14] = node_num: unused — scores[b,i,i]=1 is the strict row max, so
  // every column lands in some row's top-k and the `present` mask is all-ones.

  float* outf = (float*)d_out;
  char* ws = (char*)d_ws;
  const size_t PLANE = (size_t)Bb * Cc * Nn;  // 2M elements
  // ws layout (total ~12.8 MB, within proven bounds):
  float* gbuf = (float*)ws;                              // conv out f32, 8MB
  __bf16* gsm = (__bf16*)(ws + PLANE * 4);               // 0.25*sm*g bf16, 4MB
  unsigned long long* roib =
      (unsigned long long*)(ws + PLANE * 4 + PLANE * 2); // 1MB (8192 rows x 128B)
  // BUGFIX (r3/r4 fail): roib is 128 BYTES per row, not 16 — qtb previously
  // started 128KB in, overlapping roib rows >= 1024 (batches 1..7's masks
  // were overwritten by qt/kt -> deterministic absmax 2.875).
  float* qtb = (float*)((char*)roib + (size_t)Bb * Nn * 128);
  float* ktb = qtb + Bb * Hh * Nn;
  float* mub = ktb + Bb * Hh * Nn;
  float* rsb = mub + Bb * Nn;
  // d_out doubles as scratch: holds x^T, then out1 [B,C,N], then final out.
  float* inT  = outf;
  float* out1 = outf;

  k_roipack<<<dim3(2048), 256, 0, stream>>>(roi, sm, roib);
  k_transpose<<<dim3(16, 4, 8), 256, 0, stream>>>(input, inT);
  k_gconvq<<<dim3(16, 2, 8), 256, 0, stream>>>(inT, cw1, cb1, sm, spat, W1, b1,
                                               gbuf, gsm, qtb, ktb);
  k_apply3<0><<<dim3(8, 16, 4), 256, 0, stream>>>(gbuf, gsm, qtb, ktb,
                                                  (const unsigned char*)roib, sm, out1);
  k_gconvq<<<dim3(16, 2, 8), 256, 0, stream>>>(out1, cw2, cb2, sm, spat, W2, b2,
                                               gbuf, gsm, qtb, ktb);
  k_apply3<1><<<dim3(8, 16, 4), 256, 0, stream>>>(gbuf, gsm, qtb, ktb,
                                                  (const unsigned char*)roib, sm, outf);
  k_lnstats<<<dim3(2048), 256, 0, stream>>>(outf, mub, rsb);
  k_final<<<dim3(16, 4, 8), 256, 0, stream>>>(outf, gbuf, mub, rsb, lng, lnb);
}

// Round 6
// 134.277 us; speedup vs baseline: 2.2141x; 1.0701x over previous
//
#include <hip/hip_runtime.h>

constexpr int Bb = 8;     // batch
constexpr int Nn = 1024;  // nodes
constexpr int Cc = 256;   // channels
constexpr int Hh = 4;     // heads
constexpr int WROW = 2 * Cc + 4;  // 516, same for W1 and W2

typedef float fx4 __attribute__((ext_vector_type(4)));
typedef float f32x4 __attribute__((ext_vector_type(4)));
typedef __bf16 bf16x8 __attribute__((ext_vector_type(8)));

// ---------------------------------------------------------------------------
// Fused roipack + transpose (independent streaming work, one dispatch).
// Blocks [0,2048): pack (roi!=0 && sm[j]!=0) bits -> roib [B*N][16] u64.
// Blocks [2048,2560): transpose input [B,N,C] -> [B,C,N].
// ---------------------------------------------------------------------------
__global__ __launch_bounds__(256) void k_roitr(const float* __restrict__ roi,
                                               const float* __restrict__ sm,
                                               unsigned long long* __restrict__ roib,
                                               const float* __restrict__ in,
                                               float* __restrict__ outT) {
  __shared__ float tile[64][65];
  const int t = threadIdx.x;
  if (blockIdx.x < 2048) {
    const int gid = blockIdx.x * 4 + (t >> 6);  // row over B*N
    const int b = gid >> 10;
    const int l = t & 63;
    const float* rrow = roi + (size_t)gid * Nn;
    const float* smrow = sm + b * Nn;
    unsigned long long* orow = roib + (size_t)gid * 16;
#pragma unroll 4
    for (int jc = 0; jc < 16; ++jc) {
      float rv = rrow[jc * 64 + l];
      float sv = smrow[jc * 64 + l];
      unsigned long long m = __ballot(rv != 0.f && sv != 0.f);
      if (l == 0) orow[jc] = m;
    }
  } else {
    const int tid = blockIdx.x - 2048;
    const int n0 = (tid & 15) * 64, c0 = ((tid >> 4) & 3) * 64, b = tid >> 6;
    const int lo = t & 63, hi = t >> 6;
#pragma unroll
    for (int r = 0; r < 16; ++r) {
      int nl = hi + 4 * r;
      tile[nl][lo] = in[((b * Nn + n0 + nl) * Cc) + c0 + lo];
    }
    __syncthreads();
#pragma unroll
    for (int r = 0; r < 16; ++r) {
      int cl = hi + 4 * r;
      outT[((b * Cc + c0 + cl) * Nn) + n0 + lo] = tile[lo][cl];
    }
  }
}

// ---------------------------------------------------------------------------
// Grouped 1x1 conv + ReLU + fused qt/kt projection.
// xT [B,C,N] -> out f32 [B,C,N], gsm bf16 (= 0.25*sm*relu).
// qkt: oh==0 blocks compute qt (Wq,Wsq,+bias), oh==1 blocks compute kt.
// grid (N/64, 2, B), block 256 = 64 nodes x 4 (groups == heads).
// ---------------------------------------------------------------------------
__global__ __launch_bounds__(256) void k_gconvq(const float* __restrict__ xT,
                                                const float* __restrict__ cw,
                                                const float* __restrict__ cb,
                                                const float* __restrict__ sm,
                                                const float* __restrict__ spat,
                                                const float* __restrict__ W,
                                                const float* __restrict__ bias,
                                                float* __restrict__ out,
                                                __bf16* __restrict__ gsm,
                                                float* __restrict__ qt,
                                                float* __restrict__ kt) {
  __shared__ float xs[Cc][64];  // 64 KiB
  const int b = blockIdx.z, n0 = blockIdx.x * 64, oh = blockIdx.y;
  const int t = threadIdx.x;
  const int lo = t & 63, hi = t >> 6;
#pragma unroll 4
  for (int r = 0; r < 64; ++r) {
    int c = hi + 4 * r;
    xs[c][lo] = xT[((b * Cc + c) * Nn) + n0 + lo];
  }
  __syncthreads();
  const int g = hi, nl = lo, n = n0 + nl;

  // ---- qt/kt projection from the staged tile (oh picks q vs k) ----
  {
    const int h = hi;
    const float* wrow = W + h * WROW + oh * Cc;  // Wq or Wk
    float a = 0.f;
#pragma unroll 8
    for (int c = 0; c < Cc; ++c) a = fmaf(xs[c][nl], wrow[c], a);
    const float s0 = spat[(b * Nn + n) * 2 + 0];
    const float s1 = spat[(b * Nn + n) * 2 + 1];
    const float* wsp = W + h * WROW + 2 * Cc + oh * 2;  // Wsq or Wsk
    a += s0 * wsp[0] + s1 * wsp[1];
    if (oh == 0)
      qt[(b * Hh + h) * Nn + n] = a + bias[h];  // fold logit bias into qt
    else
      kt[(b * Hh + h) * Nn + n] = a;
  }

  // ---- grouped conv ----
  const float smv = 0.25f * sm[b * Nn + n];
  float xv[64];
#pragma unroll
  for (int ci = 0; ci < 64; ++ci) xv[ci] = xs[g * 64 + ci][nl];
  const int obase = oh * 32;
  for (int oi = 0; oi < 32; ++oi) {
    const int co = g * 64 + obase + oi;
    float acc = cb[co];
    const float4* w4 = (const float4*)&cw[co * 64];
#pragma unroll
    for (int c4 = 0; c4 < 16; ++c4) {
      float4 w = w4[c4];
      acc = fmaf(w.x, xv[c4 * 4 + 0], acc);
      acc = fmaf(w.y, xv[c4 * 4 + 1], acc);
      acc = fmaf(w.z, xv[c4 * 4 + 2], acc);
      acc = fmaf(w.w, xv[c4 * 4 + 3], acc);
    }
    const float relu = fmaxf(acc, 0.f);
    const size_t idx = ((size_t)(b * Cc + co)) * Nn + n0 + nl;
    out[idx] = relu;
    gsm[idx] = (__bf16)(smv * relu);
  }
}

// ---------------------------------------------------------------------------
// MFMA fused attention apply, BK=64 (two 32-wide MFMA K-halves per step).
// Per block (b, it, h): C[i,d] = 0.25*sum_j sig(qt[j]+kt[i])*mask[i,j]*G[d,j]
// 16 K-steps of 64 j: half the barriers of the BK=32 version; per-step
// compute (~2x) covers the distance-1 register prefetch latency.
// LDS per buf: two proven stride-40 subtiles (kk=0: j 0..31, kk=1: j 32..63).
// MODE 0: out[b,ch,i] = g[b,ch,i]*(1+fv) + C      ([B,C,N]), fv=0.25*f_i
// MODE 1: out[b,i,ch] = C + fv*g[b,ch,i]          ([B,N,C])
// grid dim3(8 b, 16 it, 4 h): linear%8 == b -> each XCD serves one batch.
// ---------------------------------------------------------------------------
template <int MODE>
__global__ __launch_bounds__(256) void k_apply4(const float* __restrict__ g,
                                                const __bf16* __restrict__ gsm,
                                                const float* __restrict__ qt,
                                                const float* __restrict__ kt,
                                                const unsigned char* __restrict__ roib,
                                                const float* __restrict__ sm,
                                                float* __restrict__ out) {
  __shared__ __align__(16) __bf16 Bs[2][2][64 * 40];  // [buf][kk][d*40+j] 20.5KB
  __shared__ __align__(16) float qts[1024];           // qt * -log2e
  const int b = blockIdx.x, it = blockIdx.y, h = blockIdx.z;
  const int t = threadIdx.x, w = t >> 6, l = t & 63;
  const int i0 = it * 64;
  const int dl = l & 15, q = l >> 4, jqf = q * 8;
  const int iA = i0 + w * 16 + dl;

  const float kvn = kt[(b * Hh + h) * Nn + iA] * -1.44269504f;
  const unsigned char* rbrow = roib + ((size_t)(b * Nn + iA)) * 128;
  const float* smrow = sm + b * Nn;

  // staging role: thread t stages row sd = t>>2, 8-j chunk sjc = t&3, both kk
  const int sd = t >> 2, sjc = t & 3;
  const __bf16* gsrc = gsm + ((size_t)(b * Cc + h * 64 + sd)) * Nn + sjc * 8;

  // qt row staged once, pre-scaled by -log2e
  {
    const float* qtrow = qt + (b * Hh + h) * Nn;
    fx4 qv = *(const fx4*)&qtrow[t * 4];
    fx4 qn;
#pragma unroll
    for (int e = 0; e < 4; ++e) qn[e] = qv[e] * -1.44269504f;
    *(fx4*)&qts[t * 4] = qn;
  }
  // stage step 0 (both K-halves)
  *(bf16x8*)&Bs[0][0][sd * 40 + sjc * 8] = *(const bf16x8*)gsrc;
  *(bf16x8*)&Bs[0][1][sd * 40 + sjc * 8] = *(const bf16x8*)(gsrc + 32);
  unsigned int rb0 = rbrow[q];
  unsigned int rb1 = rbrow[4 + q];
  __syncthreads();

  f32x4 acc[4] = {};
  for (int s = 0; s < 16; ++s) {
    const int cur = s & 1;
    bf16x8 bn0, bn1;
    unsigned int rbn0 = 0, rbn1 = 0;
    if (s < 15) {
      bn0 = *(const bf16x8*)(gsrc + (s + 1) * 64);
      bn1 = *(const bf16x8*)(gsrc + (s + 1) * 64 + 32);
      rbn0 = rbrow[(s + 1) * 8 + q];
      rbn1 = rbrow[(s + 1) * 8 + 4 + q];
    }
    // ---- K-half 0: j = s*64 + [0,32) ----
    {
      fx4 qa = *(const fx4*)&qts[s * 64 + jqf];
      fx4 qb = *(const fx4*)&qts[s * 64 + jqf + 4];
      bf16x8 af;
#pragma unroll
      for (int e = 0; e < 4; ++e) {
        float p = __builtin_amdgcn_exp2f(qa[e] + kvn);
        float sg = __builtin_amdgcn_rcpf(1.f + p);
        af[e] = (__bf16)(((rb0 >> e) & 1) ? sg : 0.f);
      }
#pragma unroll
      for (int e = 0; e < 4; ++e) {
        float p = __builtin_amdgcn_exp2f(qb[e] + kvn);
        float sg = __builtin_amdgcn_rcpf(1.f + p);
        af[4 + e] = (__bf16)(((rb0 >> (4 + e)) & 1) ? sg : 0.f);
      }
#pragma unroll
      for (int nf = 0; nf < 4; ++nf) {
        bf16x8 bv = *(const bf16x8*)&Bs[cur][0][(nf * 16 + dl) * 40 + jqf];
        acc[nf] = __builtin_amdgcn_mfma_f32_16x16x32_bf16(af, bv, acc[nf], 0, 0, 0);
      }
    }
    // ---- K-half 1: j = s*64 + [32,64) ----
    {
      fx4 qa = *(const fx4*)&qts[s * 64 + 32 + jqf];
      fx4 qb = *(const fx4*)&qts[s * 64 + 32 + jqf + 4];
      bf16x8 af;
#pragma unroll
      for (int e = 0; e < 4; ++e) {
        float p = __builtin_amdgcn_exp2f(qa[e] + kvn);
        float sg = __builtin_amdgcn_rcpf(1.f + p);
        af[e] = (__bf16)(((rb1 >> e) & 1) ? sg : 0.f);
      }
#pragma unroll
      for (int e = 0; e < 4; ++e) {
        float p = __builtin_amdgcn_exp2f(qb[e] + kvn);
        float sg = __builtin_amdgcn_rcpf(1.f + p);
        af[4 + e] = (__bf16)(((rb1 >> (4 + e)) & 1) ? sg : 0.f);
      }
#pragma unroll
      for (int nf = 0; nf < 4; ++nf) {
        bf16x8 bv = *(const bf16x8*)&Bs[cur][1][(nf * 16 + dl) * 40 + jqf];
        acc[nf] = __builtin_amdgcn_mfma_f32_16x16x32_bf16(af, bv, acc[nf], 0, 0, 0);
      }
    }
    if (s < 15) {
      *(bf16x8*)&Bs[cur ^ 1][0][sd * 40 + sjc * 8] = bn0;
      *(bf16x8*)&Bs[cur ^ 1][1][sd * 40 + sjc * 8] = bn1;
      rb0 = rbn0;
      rb1 = rbn1;
    }
    __syncthreads();
  }

  // ---- epilogue: D layout col(d)=lane&15, row(i)=(lane>>4)*4+reg ----
  const int rowg = l >> 4;
  const int iw = i0 + w * 16 + rowg * 4;
  fx4 sv = *(const fx4*)&smrow[iw];
  float fv[4];
#pragma unroll
  for (int r = 0; r < 4; ++r) fv[r] = (sv[r] == 0.f) ? 0.25f : 0.f;
  if (MODE == 0) {
#pragma unroll
    for (int nf = 0; nf < 4; ++nf) {
      const int ch = h * 64 + nf * 16 + dl;
      const size_t base = ((size_t)(b * Cc + ch)) * Nn + iw;
      fx4 gv = *(const fx4*)&g[base];
      fx4 res;
#pragma unroll
      for (int r = 0; r < 4; ++r) res[r] = gv[r] * (1.f + fv[r]) + acc[nf][r];
      *(fx4*)&out[base] = res;
    }
  } else {
#pragma unroll
    for (int nf = 0; nf < 4; ++nf) {
      const int ch = h * 64 + nf * 16 + dl;
      fx4 gv = *(const fx4*)&g[((size_t)(b * Cc + ch)) * Nn + iw];
#pragma unroll
      for (int r = 0; r < 4; ++r)
        out[((size_t)b * Nn + iw + r) * Cc + ch] = acc[nf][r] + fv[r] * gv[r];
    }
  }
}

// ---------------------------------------------------------------------------
// Fused LayerNorm stats + final residual add, one pass.
// io [B,N,C] (holds outm2T) updated in place:
//   y[b,i,c] = g2[b,c,i] + (io[b,i,c]-mu_i)*rstd_i*lng[c] + lnb[c]
// One wave owns a node's full 256-c row; butterfly shfl_xor leaves mu/rstd
// in all lanes (no LDS stats, no second stats kernel, io read exactly once).
// g2^T tile staged via LDS (gt[n][c], 2-way-max bank aliasing both sides).
// grid (8 b, 32 it), block 256 = 4 waves x 8 node-iters.
// ---------------------------------------------------------------------------
__global__ __launch_bounds__(256) void k_lnfinal(float* __restrict__ io,
                                                 const float* __restrict__ g2,
                                                 const float* __restrict__ lng,
                                                 const float* __restrict__ lnb) {
  __shared__ float gt[32][258];
  const int b = blockIdx.x, i0 = blockIdx.y * 32;
  const int t = threadIdx.x, w = t >> 6, l = t & 63;
  // stage g2^T: iter rr covers c = rr*8 + (t>>5), n = t&31
  {
    const int n = t & 31, ch = t >> 5;
#pragma unroll 8
    for (int rr = 0; rr < 32; ++rr) {
      int c = rr * 8 + ch;
      gt[n][c] = g2[((size_t)(b * Cc + c)) * Nn + i0 + n];
    }
  }
  __syncthreads();
  const fx4 lngv = *(const fx4*)&lng[l * 4];
  const fx4 lnbv = *(const fx4*)&lnb[l * 4];
#pragma unroll
  for (int r = 0; r < 8; ++r) {
    const int n = r * 4 + w;
    const size_t base = ((size_t)(b * Nn) + i0 + n) * Cc + l * 4;
    fx4 v = *(const fx4*)&io[base];
    float s = v[0] + v[1] + v[2] + v[3];
    float sq = v[0] * v[0] + v[1] * v[1] + v[2] * v[2] + v[3] * v[3];
#pragma unroll
    for (int off = 32; off; off >>= 1) {
      s += __shfl_xor(s, off, 64);
      sq += __shfl_xor(sq, off, 64);
    }
    const float m = s * (1.f / 256.f);
    const float var = sq * (1.f / 256.f) - m * m;
    const float rstd = rsqrtf(fmaxf(var, 0.f) + 1e-6f);
    fx4 gv = *(const fx4*)&gt[n][l * 4];
    fx4 res;
#pragma unroll
    for (int e = 0; e < 4; ++e)
      res[e] = gv[e] + (v[e] - m) * rstd * lngv[e] + lnbv[e];
    *(fx4*)&io[base] = res;
  }
}

// ---------------------------------------------------------------------------
extern "C" void kernel_launch(void* const* d_in, const int* in_sizes, int n_in,
                              void* d_out, int out_size, void* d_ws, size_t ws_size,
                              hipStream_t stream) {
  (void)in_sizes; (void)n_in; (void)out_size; (void)ws_size;
  const float* input = (const float*)d_in[0];
  const float* roi   = (const float*)d_in[1];   // masks_roi [B,N,N]
  const float* sm    = (const float*)d_in[2];   // score_mask [B,N]
  const float* spat  = (const float*)d_in[3];
  const float* W1    = (const float*)d_in[4];
  const float* b1    = (const float*)d_in[5];
  const float* W2    = (const float*)d_in[6];
  const float* b2    = (const float*)d_in[7];
  const float* cw1   = (const float*)d_in[8];
  const float* cb1   = (const float*)d_in[9];
  const float* cw2   = (const float*)d_in[10];
  const float* cb2   = (const float*)d_in[11];
  const float* lng   = (const float*)d_in[12];
  const float* lnb   = (const float*)d_in[13];
  // d_in[14] = node_num: unused — scores[b,i,i]=1 is the strict row max, so
  // every column lands in some row's top-k and the `present` mask is all-ones.

  float* outf = (float*)d_out;
  char* ws = (char*)d_ws;
  const size_t PLANE = (size_t)Bb * Cc * Nn;  // 2M elements
  // ws layout (~12.8 MB):
  float* gbuf = (float*)ws;                              // conv out f32, 8MB
  __bf16* gsm = (__bf16*)(ws + PLANE * 4);               // 0.25*sm*g bf16, 4MB
  unsigned long long* roib =
      (unsigned long long*)(ws + PLANE * 4 + PLANE * 2); // 1MB (8192 rows x 128B)
  float* qtb = (float*)((char*)roib + (size_t)Bb * Nn * 128);
  float* ktb = qtb + Bb * Hh * Nn;
  // d_out doubles as scratch: holds x^T, then out1 [B,C,N], then final out.
  float* inT  = outf;
  float* out1 = outf;

  k_roitr<<<dim3(2560), 256, 0, stream>>>(roi, sm, roib, input, inT);
  k_gconvq<<<dim3(16, 2, 8), 256, 0, stream>>>(inT, cw1, cb1, sm, spat, W1, b1,
                                               gbuf, gsm, qtb, ktb);
  k_apply4<0><<<dim3(8, 16, 4), 256, 0, stream>>>(gbuf, gsm, qtb, ktb,
                                                  (const unsigned char*)roib, sm, out1);
  k_gconvq<<<dim3(16, 2, 8), 256, 0, stream>>>(out1, cw2, cb2, sm, spat, W2, b2,
                                               gbuf, gsm, qtb, ktb);
  k_apply4<1><<<dim3(8, 16, 4), 256, 0, stream>>>(gbuf, gsm, qtb, ktb,
                                                  (const unsigned char*)roib, sm, outf);
  k_lnfinal<<<dim3(8, 32), 256, 0, stream>>>(outf, gbuf, lng, lnb);
}

// Round 7
// 132.995 us; speedup vs baseline: 2.2354x; 1.0096x over previous
//
#include <hip/hip_runtime.h>

constexpr int Bb = 8;     // batch
constexpr int Nn = 1024;  // nodes
constexpr int Cc = 256;   // channels
constexpr int Hh = 4;     // heads
constexpr int WROW = 2 * Cc + 4;  // 516, same for W1 and W2

typedef float fx4 __attribute__((ext_vector_type(4)));
typedef float f32x4 __attribute__((ext_vector_type(4)));
typedef __bf16 bf16x8 __attribute__((ext_vector_type(8)));

#define GLL16(src, dst)                                                      \
  __builtin_amdgcn_global_load_lds(                                          \
      (const __attribute__((address_space(1))) void*)(src),                  \
      (__attribute__((address_space(3))) void*)(dst), 16, 0, 0)

// ---------------------------------------------------------------------------
// Fused roipack + transpose (independent streaming work, one dispatch).
// Blocks [0,2048): pack (roi!=0 && sm[j]!=0) bits -> roib [B*N][16] u64.
// Blocks [2048,2560): transpose input [B,N,C] -> [B,C,N].
// ---------------------------------------------------------------------------
__global__ __launch_bounds__(256) void k_roitr(const float* __restrict__ roi,
                                               const float* __restrict__ sm,
                                               unsigned long long* __restrict__ roib,
                                               const float* __restrict__ in,
                                               float* __restrict__ outT) {
  __shared__ float tile[64][65];
  const int t = threadIdx.x;
  if (blockIdx.x < 2048) {
    const int gid = blockIdx.x * 4 + (t >> 6);  // row over B*N
    const int b = gid >> 10;
    const int l = t & 63;
    const float* rrow = roi + (size_t)gid * Nn;
    const float* smrow = sm + b * Nn;
    unsigned long long* orow = roib + (size_t)gid * 16;
#pragma unroll 4
    for (int jc = 0; jc < 16; ++jc) {
      float rv = rrow[jc * 64 + l];
      float sv = smrow[jc * 64 + l];
      unsigned long long m = __ballot(rv != 0.f && sv != 0.f);
      if (l == 0) orow[jc] = m;
    }
  } else {
    const int tid = blockIdx.x - 2048;
    const int n0 = (tid & 15) * 64, c0 = ((tid >> 4) & 3) * 64, b = tid >> 6;
    const int lo = t & 63, hi = t >> 6;
#pragma unroll
    for (int r = 0; r < 16; ++r) {
      int nl = hi + 4 * r;
      tile[nl][lo] = in[((b * Nn + n0 + nl) * Cc) + c0 + lo];
    }
    __syncthreads();
#pragma unroll
    for (int r = 0; r < 16; ++r) {
      int cl = hi + 4 * r;
      outT[((b * Cc + c0 + cl) * Nn) + n0 + lo] = tile[lo][cl];
    }
  }
}

// ---------------------------------------------------------------------------
// Grouped 1x1 conv + ReLU + fused qt/kt projection.
// xT [B,C,N] -> out f32 [B,C,N], gsm bf16 (= 0.25*sm*relu).
// qkt: oh==0 blocks compute qt (Wq,Wsq,+bias), oh==1 blocks compute kt.
// grid (N/64, 2, B), block 256 = 64 nodes x 4 (groups == heads).
// ---------------------------------------------------------------------------
__global__ __launch_bounds__(256) void k_gconvq(const float* __restrict__ xT,
                                                const float* __restrict__ cw,
                                                const float* __restrict__ cb,
                                                const float* __restrict__ sm,
                                                const float* __restrict__ spat,
                                                const float* __restrict__ W,
                                                const float* __restrict__ bias,
                                                float* __restrict__ out,
                                                __bf16* __restrict__ gsm,
                                                float* __restrict__ qt,
                                                float* __restrict__ kt) {
  __shared__ float xs[Cc][64];  // 64 KiB
  const int b = blockIdx.z, n0 = blockIdx.x * 64, oh = blockIdx.y;
  const int t = threadIdx.x;
  const int lo = t & 63, hi = t >> 6;
#pragma unroll 4
  for (int r = 0; r < 64; ++r) {
    int c = hi + 4 * r;
    xs[c][lo] = xT[((b * Cc + c) * Nn) + n0 + lo];
  }
  __syncthreads();
  const int g = hi, nl = lo, n = n0 + nl;

  // ---- qt/kt projection from the staged tile (oh picks q vs k) ----
  {
    const int h = hi;
    const float* wrow = W + h * WROW + oh * Cc;  // Wq or Wk
    float a = 0.f;
#pragma unroll 8
    for (int c = 0; c < Cc; ++c) a = fmaf(xs[c][nl], wrow[c], a);
    const float s0 = spat[(b * Nn + n) * 2 + 0];
    const float s1 = spat[(b * Nn + n) * 2 + 1];
    const float* wsp = W + h * WROW + 2 * Cc + oh * 2;  // Wsq or Wsk
    a += s0 * wsp[0] + s1 * wsp[1];
    if (oh == 0)
      qt[(b * Hh + h) * Nn + n] = a + bias[h];  // fold logit bias into qt
    else
      kt[(b * Hh + h) * Nn + n] = a;
  }

  // ---- grouped conv ----
  const float smv = 0.25f * sm[b * Nn + n];
  float xv[64];
#pragma unroll
  for (int ci = 0; ci < 64; ++ci) xv[ci] = xs[g * 64 + ci][nl];
  const int obase = oh * 32;
  for (int oi = 0; oi < 32; ++oi) {
    const int co = g * 64 + obase + oi;
    float acc = cb[co];
    const float4* w4 = (const float4*)&cw[co * 64];
#pragma unroll
    for (int c4 = 0; c4 < 16; ++c4) {
      float4 w = w4[c4];
      acc = fmaf(w.x, xv[c4 * 4 + 0], acc);
      acc = fmaf(w.y, xv[c4 * 4 + 1], acc);
      acc = fmaf(w.z, xv[c4 * 4 + 2], acc);
      acc = fmaf(w.w, xv[c4 * 4 + 3], acc);
    }
    const float relu = fmaxf(acc, 0.f);
    const size_t idx = ((size_t)(b * Cc + co)) * Nn + n0 + nl;
    out[idx] = relu;
    gsm[idx] = (__bf16)(smv * relu);
  }
}

// ---------------------------------------------------------------------------
// MFMA fused attention apply, v5: global_load_lds + counted vmcnt pipeline.
// Per block (b, it, h): C[i,d] = 0.25*sum_j sig(qt[j]+kt[i])*mask[i,j]*G[d,j]
// 16 K-steps of 64 j. Per step the ONLY loop VMEM is 2 GLLs (qt + roib rows
// pre-staged in LDS in the prologue) -> s_waitcnt vmcnt(4) provably means
// "step-s buffer landed" with distance-2 prefetch into a 4-buffer ring.
// Barrier = one asm{vmcnt(4); s_barrier} with "memory" clobber per step:
// counted wait + HW barrier + compiler fence in one — no vmcnt(0) drain.
// Ring safety: GLL(s+2) writes buf[(s+2)&3] = buf[(s-2)&3], whose readers
// finished before the step-(s-1) barrier that precedes this issue.
// LDS B layout linear [buf][kk][row][32j] (GLL lane-linear); fragment reads
// hit all 32 banks uniformly (8 lanes/4-bank group, distinct addrs = b128 floor).
// MODE 0: out[b,ch,i] = g[b,ch,i]*(1+fv) + C      ([B,C,N]), fv=0.25*f_i
// MODE 1: out[b,i,ch] = C + fv*g[b,ch,i]          ([B,N,C])
// grid dim3(8 b, 16 it, 4 h): linear%8 == b -> each XCD serves one batch.
// ---------------------------------------------------------------------------
template <int MODE>
__global__ __launch_bounds__(256) void k_apply5(const float* __restrict__ g,
                                                const __bf16* __restrict__ gsm,
                                                const float* __restrict__ qt,
                                                const float* __restrict__ kt,
                                                const unsigned char* __restrict__ roib,
                                                const float* __restrict__ sm,
                                                float* __restrict__ out) {
  __shared__ __align__(16) __bf16 Bs[4][2][64 * 32];  // 4-ring x 2 kk x 4KB = 32KB
  __shared__ __align__(16) float qts[1024];           // qt * -log2e (4KB)
  __shared__ __align__(16) unsigned char rbs[64 * 128];  // roib rows (8KB)
  const int b = blockIdx.x, it = blockIdx.y, h = blockIdx.z;
  const int t = threadIdx.x, w = t >> 6, l = t & 63;
  const int i0 = it * 64;
  const int dl = l & 15, q = l >> 4, jqf = q * 8;
  const int iA = i0 + w * 16 + dl;

  const float kvn = kt[(b * Hh + h) * Nn + iA] * -1.44269504f;
  const float* smrow = sm + b * Nn;

  // GLL staging role: thread t sources row ch = h*64 + (t>>2), chunk t&3.
  // LDS lane-linear dest == [row][chunk] since (l>>2)*32 + (l&3)*8 == l*8.
  const __bf16* gsrc = gsm + ((size_t)(b * Cc + h * 64 + (t >> 2))) * Nn + (t & 3) * 8;

  // ---- prologue: stage qt (scaled), roib rows, GLL bufs 0 & 1 ----
  {
    const float* qtrow = qt + (b * Hh + h) * Nn;
    fx4 qv = *(const fx4*)&qtrow[t * 4];
    fx4 qn;
#pragma unroll
    for (int e = 0; e < 4; ++e) qn[e] = qv[e] * -1.44269504f;
    *(fx4*)&qts[t * 4] = qn;
  }
  {
    const int r = t >> 2, c = (t & 3) * 32;  // 32B of row r's 128B mask
    const char* src = (const char*)(roib + ((size_t)(b * Nn + i0 + r)) * 128) + c;
    *(int4*)&rbs[r * 128 + c] = *(const int4*)src;
    *(int4*)&rbs[r * 128 + c + 16] = *(const int4*)(src + 16);
  }
  GLL16(gsrc, &Bs[0][0][w * 512]);
  GLL16(gsrc + 32, &Bs[0][1][w * 512]);
  GLL16(gsrc + 64, &Bs[1][0][w * 512]);
  GLL16(gsrc + 96, &Bs[1][1][w * 512]);
  asm volatile("s_waitcnt vmcnt(2)\n\ts_barrier" ::: "memory");
  __builtin_amdgcn_sched_barrier(0);

  const int rbbase = (w * 16 + dl) * 128;
  f32x4 acc[4] = {};

  // ---- main loop: 16 K-steps of 64 j, one barrier per step ----
  for (int s = 0; s < 16; ++s) {
    const int buf = s & 3;
    // prefetch step s+2 (wrap keeps VMEM count uniform; ring-safe)
    {
      const int jb = ((s + 2) & 15) * 64;
      const int nb = (s + 2) & 3;
      GLL16(gsrc + jb, &Bs[nb][0][w * 512]);
      GLL16(gsrc + jb + 32, &Bs[nb][1][w * 512]);
    }
    // A-fragments for both K-halves (overlaps GLL flight)
    const unsigned int rb0 = rbs[rbbase + s * 8 + q];
    const unsigned int rb1 = rbs[rbbase + s * 8 + 4 + q];
    bf16x8 af0, af1;
    {
      fx4 qa = *(const fx4*)&qts[s * 64 + jqf];
      fx4 qb = *(const fx4*)&qts[s * 64 + jqf + 4];
#pragma unroll
      for (int e = 0; e < 4; ++e) {
        float sg = __builtin_amdgcn_rcpf(1.f + __builtin_amdgcn_exp2f(qa[e] + kvn));
        af0[e] = (__bf16)(((rb0 >> e) & 1) ? sg : 0.f);
      }
#pragma unroll
      for (int e = 0; e < 4; ++e) {
        float sg = __builtin_amdgcn_rcpf(1.f + __builtin_amdgcn_exp2f(qb[e] + kvn));
        af0[4 + e] = (__bf16)(((rb0 >> (4 + e)) & 1) ? sg : 0.f);
      }
      fx4 qc = *(const fx4*)&qts[s * 64 + 32 + jqf];
      fx4 qd = *(const fx4*)&qts[s * 64 + 32 + jqf + 4];
#pragma unroll
      for (int e = 0; e < 4; ++e) {
        float sg = __builtin_amdgcn_rcpf(1.f + __builtin_amdgcn_exp2f(qc[e] + kvn));
        af1[e] = (__bf16)(((rb1 >> e) & 1) ? sg : 0.f);
      }
#pragma unroll
      for (int e = 0; e < 4; ++e) {
        float sg = __builtin_amdgcn_rcpf(1.f + __builtin_amdgcn_exp2f(qd[e] + kvn));
        af1[4 + e] = (__bf16)(((rb1 >> (4 + e)) & 1) ? sg : 0.f);
      }
    }
    // counted wait (step-s GLLs landed; s+1/s+2 stay in flight) + barrier
    asm volatile("s_waitcnt vmcnt(4)\n\ts_barrier" ::: "memory");
    __builtin_amdgcn_sched_barrier(0);
    // MFMA cluster on buf s
#pragma unroll
    for (int nf = 0; nf < 4; ++nf) {
      bf16x8 bv = *(const bf16x8*)&Bs[buf][0][(nf * 16 + dl) * 32 + jqf];
      acc[nf] = __builtin_amdgcn_mfma_f32_16x16x32_bf16(af0, bv, acc[nf], 0, 0, 0);
    }
#pragma unroll
    for (int nf = 0; nf < 4; ++nf) {
      bf16x8 bv = *(const bf16x8*)&Bs[buf][1][(nf * 16 + dl) * 32 + jqf];
      acc[nf] = __builtin_amdgcn_mfma_f32_16x16x32_bf16(af1, bv, acc[nf], 0, 0, 0);
    }
  }

  // ---- epilogue: D layout col(d)=lane&15, row(i)=(lane>>4)*4+reg ----
  const int rowg = l >> 4;
  const int iw = i0 + w * 16 + rowg * 4;
  fx4 sv = *(const fx4*)&smrow[iw];
  float fv[4];
#pragma unroll
  for (int r = 0; r < 4; ++r) fv[r] = (sv[r] == 0.f) ? 0.25f : 0.f;
  if (MODE == 0) {
#pragma unroll
    for (int nf = 0; nf < 4; ++nf) {
      const int ch = h * 64 + nf * 16 + dl;
      const size_t base = ((size_t)(b * Cc + ch)) * Nn + iw;
      fx4 gv = *(const fx4*)&g[base];
      fx4 res;
#pragma unroll
      for (int r = 0; r < 4; ++r) res[r] = gv[r] * (1.f + fv[r]) + acc[nf][r];
      *(fx4*)&out[base] = res;
    }
  } else {
#pragma unroll
    for (int nf = 0; nf < 4; ++nf) {
      const int ch = h * 64 + nf * 16 + dl;
      fx4 gv = *(const fx4*)&g[((size_t)(b * Cc + ch)) * Nn + iw];
#pragma unroll
      for (int r = 0; r < 4; ++r)
        out[((size_t)b * Nn + iw + r) * Cc + ch] = acc[nf][r] + fv[r] * gv[r];
    }
  }
}

// ---------------------------------------------------------------------------
// Fused LayerNorm stats + final residual add, one pass.
// io [B,N,C] (holds outm2T) updated in place:
//   y[b,i,c] = g2[b,c,i] + (io[b,i,c]-mu_i)*rstd_i*lng[c] + lnb[c]
// grid (8 b, 32 it), block 256 = 4 waves x 8 node-iters.
// ---------------------------------------------------------------------------
__global__ __launch_bounds__(256) void k_lnfinal(float* __restrict__ io,
                                                 const float* __restrict__ g2,
                                                 const float* __restrict__ lng,
                                                 const float* __restrict__ lnb) {
  __shared__ float gt[32][258];
  const int b = blockIdx.x, i0 = blockIdx.y * 32;
  const int t = threadIdx.x, w = t >> 6, l = t & 63;
  {
    const int n = t & 31, ch = t >> 5;
#pragma unroll 8
    for (int rr = 0; rr < 32; ++rr) {
      int c = rr * 8 + ch;
      gt[n][c] = g2[((size_t)(b * Cc + c)) * Nn + i0 + n];
    }
  }
  __syncthreads();
  const fx4 lngv = *(const fx4*)&lng[l * 4];
  const fx4 lnbv = *(const fx4*)&lnb[l * 4];
#pragma unroll
  for (int r = 0; r < 8; ++r) {
    const int n = r * 4 + w;
    const size_t base = ((size_t)(b * Nn) + i0 + n) * Cc + l * 4;
    fx4 v = *(const fx4*)&io[base];
    float s = v[0] + v[1] + v[2] + v[3];
    float sq = v[0] * v[0] + v[1] * v[1] + v[2] * v[2] + v[3] * v[3];
#pragma unroll
    for (int off = 32; off; off >>= 1) {
      s += __shfl_xor(s, off, 64);
      sq += __shfl_xor(sq, off, 64);
    }
    const float m = s * (1.f / 256.f);
    const float var = sq * (1.f / 256.f) - m * m;
    const float rstd = rsqrtf(fmaxf(var, 0.f) + 1e-6f);
    fx4 gv = *(const fx4*)&gt[n][l * 4];
    fx4 res;
#pragma unroll
    for (int e = 0; e < 4; ++e)
      res[e] = gv[e] + (v[e] - m) * rstd * lngv[e] + lnbv[e];
    *(fx4*)&io[base] = res;
  }
}

// ---------------------------------------------------------------------------
extern "C" void kernel_launch(void* const* d_in, const int* in_sizes, int n_in,
                              void* d_out, int out_size, void* d_ws, size_t ws_size,
                              hipStream_t stream) {
  (void)in_sizes; (void)n_in; (void)out_size; (void)ws_size;
  const float* input = (const float*)d_in[0];
  const float* roi   = (const float*)d_in[1];   // masks_roi [B,N,N]
  const float* sm    = (const float*)d_in[2];   // score_mask [B,N]
  const float* spat  = (const float*)d_in[3];
  const float* W1    = (const float*)d_in[4];
  const float* b1    = (const float*)d_in[5];
  const float* W2    = (const float*)d_in[6];
  const float* b2    = (const float*)d_in[7];
  const float* cw1   = (const float*)d_in[8];
  const float* cb1   = (const float*)d_in[9];
  const float* cw2   = (const float*)d_in[10];
  const float* cb2   = (const float*)d_in[11];
  const float* lng   = (const float*)d_in[12];
  const float* lnb   = (const float*)d_in[13];
  // d_in[14] = node_num: unused — scores[b,i,i]=1 is the strict row max, so
  // every column lands in some row's top-k and the `present` mask is all-ones.

  float* outf = (float*)d_out;
  char* ws = (char*)d_ws;
  const size_t PLANE = (size_t)Bb * Cc * Nn;  // 2M elements
  // ws layout (~12.8 MB):
  float* gbuf = (float*)ws;                              // conv out f32, 8MB
  __bf16* gsm = (__bf16*)(ws + PLANE * 4);               // 0.25*sm*g bf16, 4MB
  unsigned long long* roib =
      (unsigned long long*)(ws + PLANE * 4 + PLANE * 2); // 1MB (8192 rows x 128B)
  float* qtb = (float*)((char*)roib + (size_t)Bb * Nn * 128);
  float* ktb = qtb + Bb * Hh * Nn;
  // d_out doubles as scratch: holds x^T, then out1 [B,C,N], then final out.
  float* inT  = outf;
  float* out1 = outf;

  k_roitr<<<dim3(2560), 256, 0, stream>>>(roi, sm, roib, input, inT);
  k_gconvq<<<dim3(16, 2, 8), 256, 0, stream>>>(inT, cw1, cb1, sm, spat, W1, b1,
                                               gbuf, gsm, qtb, ktb);
  k_apply5<0><<<dim3(8, 16, 4), 256, 0, stream>>>(gbuf, gsm, qtb, ktb,
                                                  (const unsigned char*)roib, sm, out1);
  k_gconvq<<<dim3(16, 2, 8), 256, 0, stream>>>(out1, cw2, cb2, sm, spat, W2, b2,
                                               gbuf, gsm, qtb, ktb);
  k_apply5<1><<<dim3(8, 16, 4), 256, 0, stream>>>(gbuf, gsm, qtb, ktb,
                                                  (const unsigned char*)roib, sm, outf);
  k_lnfinal<<<dim3(8, 32), 256, 0, stream>>>(outf, gbuf, lng, lnb);
}

// Round 8
// 128.700 us; speedup vs baseline: 2.3100x; 1.0334x over previous
//
#include <hip/hip_runtime.h>

constexpr int Bb = 8;     // batch
constexpr int Nn = 1024;  // nodes
constexpr int Cc = 256;   // channels
constexpr int Hh = 4;     // heads
constexpr int WROW = 2 * Cc + 4;  // 516, same for W1 and W2

typedef float fx4 __attribute__((ext_vector_type(4)));
typedef float f32x4 __attribute__((ext_vector_type(4)));
typedef __bf16 bf16x8 __attribute__((ext_vector_type(8)));

#define GLL16(src, dst)                                                      \
  __builtin_amdgcn_global_load_lds(                                          \
      (const __attribute__((address_space(1))) void*)(src),                  \
      (__attribute__((address_space(3))) void*)(dst), 16, 0, 0)

// ---------------------------------------------------------------------------
// Fused roipack + transpose (independent streaming work, one dispatch).
// Blocks [0,2048): pack (roi!=0 && sm[j]!=0) bits -> roib [B*N][16] u64.
// Blocks [2048,2560): transpose input [B,N,C] -> [B,C,N].
// ---------------------------------------------------------------------------
__global__ __launch_bounds__(256) void k_roitr(const float* __restrict__ roi,
                                               const float* __restrict__ sm,
                                               unsigned long long* __restrict__ roib,
                                               const float* __restrict__ in,
                                               float* __restrict__ outT) {
  __shared__ float tile[64][65];
  const int t = threadIdx.x;
  if (blockIdx.x < 2048) {
    const int gid = blockIdx.x * 4 + (t >> 6);  // row over B*N
    const int b = gid >> 10;
    const int l = t & 63;
    const float* rrow = roi + (size_t)gid * Nn;
    const float* smrow = sm + b * Nn;
    unsigned long long* orow = roib + (size_t)gid * 16;
#pragma unroll 4
    for (int jc = 0; jc < 16; ++jc) {
      float rv = rrow[jc * 64 + l];
      float sv = smrow[jc * 64 + l];
      unsigned long long m = __ballot(rv != 0.f && sv != 0.f);
      if (l == 0) orow[jc] = m;
    }
  } else {
    const int tid = blockIdx.x - 2048;
    const int n0 = (tid & 15) * 64, c0 = ((tid >> 4) & 3) * 64, b = tid >> 6;
    const int lo = t & 63, hi = t >> 6;
#pragma unroll
    for (int r = 0; r < 16; ++r) {
      int nl = hi + 4 * r;
      tile[nl][lo] = in[((b * Nn + n0 + nl) * Cc) + c0 + lo];
    }
    __syncthreads();
#pragma unroll
    for (int r = 0; r < 16; ++r) {
      int cl = hi + 4 * r;
      outT[((b * Cc + c0 + cl) * Nn) + n0 + lo] = tile[lo][cl];
    }
  }
}

// ---------------------------------------------------------------------------
// Grouped 1x1 conv + ReLU + fused qt/kt projection.
// xT [B,C,N] -> out f32 [B,C,N], gsm bf16 (= 0.25*sm*relu).
// qkt: oh==0 blocks compute qt (Wq,Wsq,+bias), oh==1 blocks compute kt.
// grid (N/64, 2, B), block 256 = 64 nodes x 4 (groups == heads).
// ---------------------------------------------------------------------------
__global__ __launch_bounds__(256) void k_gconvq(const float* __restrict__ xT,
                                                const float* __restrict__ cw,
                                                const float* __restrict__ cb,
                                                const float* __restrict__ sm,
                                                const float* __restrict__ spat,
                                                const float* __restrict__ W,
                                                const float* __restrict__ bias,
                                                float* __restrict__ out,
                                                __bf16* __restrict__ gsm,
                                                float* __restrict__ qt,
                                                float* __restrict__ kt) {
  __shared__ float xs[Cc][64];  // 64 KiB
  const int b = blockIdx.z, n0 = blockIdx.x * 64, oh = blockIdx.y;
  const int t = threadIdx.x;
  const int lo = t & 63, hi = t >> 6;
#pragma unroll 4
  for (int r = 0; r < 64; ++r) {
    int c = hi + 4 * r;
    xs[c][lo] = xT[((b * Cc + c) * Nn) + n0 + lo];
  }
  __syncthreads();
  const int g = hi, nl = lo, n = n0 + nl;

  // ---- qt/kt projection from the staged tile (oh picks q vs k) ----
  {
    const int h = hi;
    const float* wrow = W + h * WROW + oh * Cc;  // Wq or Wk
    float a = 0.f;
#pragma unroll 8
    for (int c = 0; c < Cc; ++c) a = fmaf(xs[c][nl], wrow[c], a);
    const float s0 = spat[(b * Nn + n) * 2 + 0];
    const float s1 = spat[(b * Nn + n) * 2 + 1];
    const float* wsp = W + h * WROW + 2 * Cc + oh * 2;  // Wsq or Wsk
    a += s0 * wsp[0] + s1 * wsp[1];
    if (oh == 0)
      qt[(b * Hh + h) * Nn + n] = a + bias[h];  // fold logit bias into qt
    else
      kt[(b * Hh + h) * Nn + n] = a;
  }

  // ---- grouped conv ----
  const float smv = 0.25f * sm[b * Nn + n];
  float xv[64];
#pragma unroll
  for (int ci = 0; ci < 64; ++ci) xv[ci] = xs[g * 64 + ci][nl];
  const int obase = oh * 32;
  for (int oi = 0; oi < 32; ++oi) {
    const int co = g * 64 + obase + oi;
    float acc = cb[co];
    const float4* w4 = (const float4*)&cw[co * 64];
#pragma unroll
    for (int c4 = 0; c4 < 16; ++c4) {
      float4 w = w4[c4];
      acc = fmaf(w.x, xv[c4 * 4 + 0], acc);
      acc = fmaf(w.y, xv[c4 * 4 + 1], acc);
      acc = fmaf(w.z, xv[c4 * 4 + 2], acc);
      acc = fmaf(w.w, xv[c4 * 4 + 3], acc);
    }
    const float relu = fmaxf(acc, 0.f);
    const size_t idx = ((size_t)(b * Cc + co)) * Nn + n0 + nl;
    out[idx] = relu;
    gsm[idx] = (__bf16)(smv * relu);
  }
}

// ---------------------------------------------------------------------------
// MFMA fused attention apply, v6: 8 waves, j-split for 2x occupancy.
// Per block (b, it, h): C[i,d] = 0.25*sum_j sig(qt[j]+kt[i])*mask[i,j]*G[d,j]
// Waves 0-3 (group 0) sum j in [0,512); waves 4-7 (group 1) j in [512,1024);
// partial f32 accs combined through LDS at the end. 8 K-steps of 64 j per
// wave (vs 16 in v5): halves the per-wave serial chain AND doubles waves/CU
// (16/CU = 4/SIMD; LDS 60KB -> 2 blocks/CU).
// Staging: per group a PRIVATE 3-buffer LDS ring, each wave issues exactly 2
// GLLs per step for its 16 rows -> per-wave vmcnt is self-contained:
// at barrier B_s outstanding = 2 (the step-(s+1) pair) -> vmcnt(2) ==
// "buf s landed". GLL issue is AFTER the barrier, so the 3-ring is race-free:
// buf (s+2)%3 was last read in step s-1, strictly before B_s.
// qt (pre-scaled) and roib rows pre-staged in LDS (prologue + __syncthreads).
// MODE 0: out[b,ch,i] = g[b,ch,i]*(1+fv) + C      ([B,C,N]), fv=0.25*f_i
// MODE 1: out[b,i,ch] = C + fv*g[b,ch,i]          ([B,N,C])
// grid dim3(8 b, 16 it, 4 h): linear%8 == b -> each XCD serves one batch.
// ---------------------------------------------------------------------------
template <int MODE>
__global__ __launch_bounds__(512, 4) void k_apply6(const float* __restrict__ g,
                                                   const __bf16* __restrict__ gsm,
                                                   const float* __restrict__ qt,
                                                   const float* __restrict__ kt,
                                                   const unsigned char* __restrict__ roib,
                                                   const float* __restrict__ sm,
                                                   float* __restrict__ out) {
  // [group][buf][kk][64 rows * 32 j] bf16 = 48KB
  __shared__ __align__(16) __bf16 Bs[2][3][2][2048];
  __shared__ __align__(16) float qts[1024];              // qt * -log2e (4KB)
  __shared__ __align__(16) unsigned char rbs[64 * 128];  // roib rows (8KB)
  const int b = blockIdx.x, it = blockIdx.y, h = blockIdx.z;
  const int t = threadIdx.x, w = t >> 6, l = t & 63;
  const int grp = w >> 2, wq = w & 3;
  const int i0 = it * 64;
  const int dl = l & 15, q = l >> 4, jqf = q * 8;
  const int iA = i0 + wq * 16 + dl;

  const float kvn = kt[(b * Hh + h) * Nn + iA] * -1.44269504f;
  const float* smrow = sm + b * Nn;

  // GLL staging: wave (grp,wq) stages rows wq*16 + (l>>2), j-chunk (l&3)*8
  // of its group's j-half. LDS dest lane-linear == [row][chunk].
  const __bf16* gsrc = gsm + ((size_t)(b * Cc + h * 64 + wq * 16 + (l >> 2))) * Nn
                       + grp * 512 + (l & 3) * 8;
  __bf16* ring = &Bs[grp][0][0][0];
  const int wdst = wq * 512;

  // ---- prologue: stage qts (scaled), rbs, GLL bufs 0 & 1, full sync ----
  {
    const float2 qv = *(const float2*)&qt[(b * Hh + h) * Nn + t * 2];
    qts[t * 2 + 0] = qv.x * -1.44269504f;
    qts[t * 2 + 1] = qv.y * -1.44269504f;
  }
  {
    const int r = t >> 3, c = (t & 7) * 16;
    const char* src = (const char*)roib + ((size_t)(b * Nn + i0 + r)) * 128 + c;
    *(int4*)&rbs[r * 128 + c] = *(const int4*)src;
  }
  GLL16(gsrc, ring + 0 * 4096 + 0 * 2048 + wdst);
  GLL16(gsrc + 32, ring + 0 * 4096 + 1 * 2048 + wdst);
  GLL16(gsrc + 64, ring + 1 * 4096 + 0 * 2048 + wdst);
  GLL16(gsrc + 96, ring + 1 * 4096 + 1 * 2048 + wdst);
  __syncthreads();  // drains prologue GLLs + makes qts/rbs visible (one-time)

  const int rbbase = (wq * 16 + dl) * 128 + grp * 64;
  f32x4 acc[4] = {};
  int cur = 0;  // s % 3

  // ---- main loop: 8 K-steps of 64 j per wave ----
  for (int s = 0; s < 8; ++s) {
    const int jb = grp * 512 + s * 64;
    // A-fragments (LDS qts/rbs, stable data — safe before the barrier)
    const unsigned int rb0 = rbs[rbbase + s * 8 + q];
    const unsigned int rb1 = rbs[rbbase + s * 8 + 4 + q];
    bf16x8 af0, af1;
    {
      fx4 qa = *(const fx4*)&qts[jb + jqf];
      fx4 qb = *(const fx4*)&qts[jb + jqf + 4];
#pragma unroll
      for (int e = 0; e < 4; ++e) {
        float sg = __builtin_amdgcn_rcpf(1.f + __builtin_amdgcn_exp2f(qa[e] + kvn));
        af0[e] = (__bf16)(((rb0 >> e) & 1) ? sg : 0.f);
      }
#pragma unroll
      for (int e = 0; e < 4; ++e) {
        float sg = __builtin_amdgcn_rcpf(1.f + __builtin_amdgcn_exp2f(qb[e] + kvn));
        af0[4 + e] = (__bf16)(((rb0 >> (4 + e)) & 1) ? sg : 0.f);
      }
      fx4 qc = *(const fx4*)&qts[jb + 32 + jqf];
      fx4 qd = *(const fx4*)&qts[jb + 32 + jqf + 4];
#pragma unroll
      for (int e = 0; e < 4; ++e) {
        float sg = __builtin_amdgcn_rcpf(1.f + __builtin_amdgcn_exp2f(qc[e] + kvn));
        af1[e] = (__bf16)(((rb1 >> e) & 1) ? sg : 0.f);
      }
#pragma unroll
      for (int e = 0; e < 4; ++e) {
        float sg = __builtin_amdgcn_rcpf(1.f + __builtin_amdgcn_exp2f(qd[e] + kvn));
        af1[4 + e] = (__bf16)(((rb1 >> (4 + e)) & 1) ? sg : 0.f);
      }
    }
    // buf s landed iff <=2 outstanding (only the s+1 pair may remain)
    asm volatile("s_waitcnt vmcnt(2)\n\ts_barrier" ::: "memory");
    __builtin_amdgcn_sched_barrier(0);
    // prefetch step s+2 AFTER the barrier (ring-reuse race-free, see header)
    if (s < 6) {
      const int pf = (cur == 0) ? 2 : cur - 1;  // (s+2)%3
      GLL16(gsrc + (s + 2) * 64, ring + pf * 4096 + 0 * 2048 + wdst);
      GLL16(gsrc + (s + 2) * 64 + 32, ring + pf * 4096 + 1 * 2048 + wdst);
    }
    // MFMA cluster on buf s
    const __bf16* bp = ring + cur * 4096;
#pragma unroll
    for (int nf = 0; nf < 4; ++nf) {
      bf16x8 bv = *(const bf16x8*)(bp + (nf * 16 + dl) * 32 + jqf);
      acc[nf] = __builtin_amdgcn_mfma_f32_16x16x32_bf16(af0, bv, acc[nf], 0, 0, 0);
    }
#pragma unroll
    for (int nf = 0; nf < 4; ++nf) {
      bf16x8 bv = *(const bf16x8*)(bp + 2048 + (nf * 16 + dl) * 32 + jqf);
      acc[nf] = __builtin_amdgcn_mfma_f32_16x16x32_bf16(af1, bv, acc[nf], 0, 0, 0);
    }
    cur = (cur == 2) ? 0 : cur + 1;
  }

  // ---- combine group partials through LDS (ring area reused post-drain) ----
  __syncthreads();
  float* accS = (float*)&Bs[0][0][0][0];  // 4 wq x 64 l x 4 nf x f32x4 = 16KB
  if (grp == 1) {
#pragma unroll
    for (int nf = 0; nf < 4; ++nf)
      *(f32x4*)&accS[((wq * 64 + l) * 4 + nf) * 4] = acc[nf];
  }
  __syncthreads();
  if (grp == 0) {
#pragma unroll
    for (int nf = 0; nf < 4; ++nf)
      acc[nf] += *(const f32x4*)&accS[((wq * 64 + l) * 4 + nf) * 4];

    // epilogue: D layout col(d)=lane&15, row(i)=(lane>>4)*4+reg
    const int iw = i0 + wq * 16 + (l >> 4) * 4;
    fx4 sv = *(const fx4*)&smrow[iw];
    float fv[4];
#pragma unroll
    for (int r = 0; r < 4; ++r) fv[r] = (sv[r] == 0.f) ? 0.25f : 0.f;
    if (MODE == 0) {
#pragma unroll
      for (int nf = 0; nf < 4; ++nf) {
        const int ch = h * 64 + nf * 16 + dl;
        const size_t base = ((size_t)(b * Cc + ch)) * Nn + iw;
        fx4 gv = *(const fx4*)&g[base];
        fx4 res;
#pragma unroll
        for (int r = 0; r < 4; ++r) res[r] = gv[r] * (1.f + fv[r]) + acc[nf][r];
        *(fx4*)&out[base] = res;
      }
    } else {
#pragma unroll
      for (int nf = 0; nf < 4; ++nf) {
        const int ch = h * 64 + nf * 16 + dl;
        fx4 gv = *(const fx4*)&g[((size_t)(b * Cc + ch)) * Nn + iw];
#pragma unroll
        for (int r = 0; r < 4; ++r)
          out[((size_t)b * Nn + iw + r) * Cc + ch] = acc[nf][r] + fv[r] * gv[r];
      }
    }
  }
}

// ---------------------------------------------------------------------------
// Fused LayerNorm stats + final residual add, one pass.
// io [B,N,C] (holds outm2T) updated in place:
//   y[b,i,c] = g2[b,c,i] + (io[b,i,c]-mu_i)*rstd_i*lng[c] + lnb[c]
// grid (8 b, 32 it), block 256 = 4 waves x 8 node-iters.
// ---------------------------------------------------------------------------
__global__ __launch_bounds__(256) void k_lnfinal(float* __restrict__ io,
                                                 const float* __restrict__ g2,
                                                 const float* __restrict__ lng,
                                                 const float* __restrict__ lnb) {
  __shared__ float gt[32][258];
  const int b = blockIdx.x, i0 = blockIdx.y * 32;
  const int t = threadIdx.x, w = t >> 6, l = t & 63;
  {
    const int n = t & 31, ch = t >> 5;
#pragma unroll 8
    for (int rr = 0; rr < 32; ++rr) {
      int c = rr * 8 + ch;
      gt[n][c] = g2[((size_t)(b * Cc + c)) * Nn + i0 + n];
    }
  }
  __syncthreads();
  const fx4 lngv = *(const fx4*)&lng[l * 4];
  const fx4 lnbv = *(const fx4*)&lnb[l * 4];
#pragma unroll
  for (int r = 0; r < 8; ++r) {
    const int n = r * 4 + w;
    const size_t base = ((size_t)(b * Nn) + i0 + n) * Cc + l * 4;
    fx4 v = *(const fx4*)&io[base];
    float s = v[0] + v[1] + v[2] + v[3];
    float sq = v[0] * v[0] + v[1] * v[1] + v[2] * v[2] + v[3] * v[3];
#pragma unroll
    for (int off = 32; off; off >>= 1) {
      s += __shfl_xor(s, off, 64);
      sq += __shfl_xor(sq, off, 64);
    }
    const float m = s * (1.f / 256.f);
    const float var = sq * (1.f / 256.f) - m * m;
    const float rstd = rsqrtf(fmaxf(var, 0.f) + 1e-6f);
    fx4 gv = *(const fx4*)&gt[n][l * 4];
    fx4 res;
#pragma unroll
    for (int e = 0; e < 4; ++e)
      res[e] = gv[e] + (v[e] - m) * rstd * lngv[e] + lnbv[e];
    *(fx4*)&io[base] = res;
  }
}

// ---------------------------------------------------------------------------
extern "C" void kernel_launch(void* const* d_in, const int* in_sizes, int n_in,
                              void* d_out, int out_size, void* d_ws, size_t ws_size,
                              hipStream_t stream) {
  (void)in_sizes; (void)n_in; (void)out_size; (void)ws_size;
  const float* input = (const float*)d_in[0];
  const float* roi   = (const float*)d_in[1];   // masks_roi [B,N,N]
  const float* sm    = (const float*)d_in[2];   // score_mask [B,N]
  const float* spat  = (const float*)d_in[3];
  const float* W1    = (const float*)d_in[4];
  const float* b1    = (const float*)d_in[5];
  const float* W2    = (const float*)d_in[6];
  const float* b2    = (const float*)d_in[7];
  const float* cw1   = (const float*)d_in[8];
  const float* cb1   = (const float*)d_in[9];
  const float* cw2   = (const float*)d_in[10];
  const float* cb2   = (const float*)d_in[11];
  const float* lng   = (const float*)d_in[12];
  const float* lnb   = (const float*)d_in[13];
  // d_in[14] = node_num: unused — scores[b,i,i]=1 is the strict row max, so
  // every column lands in some row's top-k and the `present` mask is all-ones.

  float* outf = (float*)d_out;
  char* ws = (char*)d_ws;
  const size_t PLANE = (size_t)Bb * Cc * Nn;  // 2M elements
  // ws layout (~12.8 MB):
  float* gbuf = (float*)ws;                              // conv out f32, 8MB
  __bf16* gsm = (__bf16*)(ws + PLANE * 4);               // 0.25*sm*g bf16, 4MB
  unsigned long long* roib =
      (unsigned long long*)(ws + PLANE * 4 + PLANE * 2); // 1MB (8192 rows x 128B)
  float* qtb = (float*)((char*)roib + (size_t)Bb * Nn * 128);
  float* ktb = qtb + Bb * Hh * Nn;
  // d_out doubles as scratch: holds x^T, then out1 [B,C,N], then final out.
  float* inT  = outf;
  float* out1 = outf;

  k_roitr<<<dim3(2560), 256, 0, stream>>>(roi, sm, roib, input, inT);
  k_gconvq<<<dim3(16, 2, 8), 256, 0, stream>>>(inT, cw1, cb1, sm, spat, W1, b1,
                                               gbuf, gsm, qtb, ktb);
  k_apply6<0><<<dim3(8, 16, 4), 512, 0, stream>>>(gbuf, gsm, qtb, ktb,
                                                  (const unsigned char*)roib, sm, out1);
  k_gconvq<<<dim3(16, 2, 8), 256, 0, stream>>>(out1, cw2, cb2, sm, spat, W2, b2,
                                               gbuf, gsm, qtb, ktb);
  k_apply6<1><<<dim3(8, 16, 4), 512, 0, stream>>>(gbuf, gsm, qtb, ktb,
                                                  (const unsigned char*)roib, sm, outf);
  k_lnfinal<<<dim3(8, 32), 256, 0, stream>>>(outf, gbuf, lng, lnb);
}

// Round 9
// 122.443 us; speedup vs baseline: 2.4280x; 1.0511x over previous
//
#include <hip/hip_runtime.h>

constexpr int Bb = 8;     // batch
constexpr int Nn = 1024;  // nodes
constexpr int Cc = 256;   // channels
constexpr int Hh = 4;     // heads
constexpr int WROW = 2 * Cc + 4;  // 516, same for W1 and W2

typedef float fx4 __attribute__((ext_vector_type(4)));
typedef float f32x4 __attribute__((ext_vector_type(4)));
typedef __bf16 bf16x8 __attribute__((ext_vector_type(8)));

#define GLL16(src, dst)                                                      \
  __builtin_amdgcn_global_load_lds(                                          \
      (const __attribute__((address_space(1))) void*)(src),                  \
      (__attribute__((address_space(3))) void*)(dst), 16, 0, 0)

// ---------------------------------------------------------------------------
// Fused roipack + transpose.
// Blocks [0,2048): pack roi bits over COMPACTED j (order-preserving list of
//   j with sm[b,j]!=0, recomputed locally from sm via 16 ballots) into
//   roib [B*N][16] u64. Words beyond ceil(cnt/64) are zero.
// Blocks [2048,2560): transpose input [B,N,C] -> [B,C,N].
// ---------------------------------------------------------------------------
__global__ __launch_bounds__(256) void k_roitr(const float* __restrict__ roi,
                                               const float* __restrict__ sm,
                                               unsigned long long* __restrict__ roib,
                                               const float* __restrict__ in,
                                               float* __restrict__ outT) {
  __shared__ float tile[64][65];
  __shared__ short jmapS[1024];
  __shared__ int cntS;
  const int t = threadIdx.x;
  if (blockIdx.x < 2048) {
    const int gid = blockIdx.x * 4 + (t >> 6);  // row over B*N (4 rows, same b)
    const int b = gid >> 10;
    const int l = t & 63;
    // wave 0 builds the compacted j-map for batch b
    if ((t >> 6) == 0) {
      int base = 0;
#pragma unroll
      for (int jc = 0; jc < 16; ++jc) {
        const int j = jc * 64 + l;
        const bool act = sm[b * Nn + j] != 0.f;
        const unsigned long long m = __ballot(act);
        if (act) jmapS[base + __popcll(m & ((1ull << l) - 1))] = (short)j;
        base += __popcll(m);
      }
      if (l == 0) cntS = base;
    }
    __syncthreads();
    const int cnt = cntS;
    const float* rrow = roi + (size_t)gid * Nn;
    unsigned long long* orow = roib + (size_t)gid * 16;
#pragma unroll 4
    for (int pc = 0; pc < 16; ++pc) {
      const int idx = pc * 64 + l;
      const bool valid = idx < cnt;
      const int j = valid ? jmapS[idx] : 0;
      const bool bit = valid && (rrow[j] != 0.f);
      unsigned long long m = __ballot(bit);
      if (l == 0) orow[pc] = m;
    }
  } else {
    const int tid = blockIdx.x - 2048;
    const int n0 = (tid & 15) * 64, c0 = ((tid >> 4) & 3) * 64, b = tid >> 6;
    const int lo = t & 63, hi = t >> 6;
#pragma unroll
    for (int r = 0; r < 16; ++r) {
      int nl = hi + 4 * r;
      tile[nl][lo] = in[((b * Nn + n0 + nl) * Cc) + c0 + lo];
    }
    __syncthreads();
#pragma unroll
    for (int r = 0; r < 16; ++r) {
      int cl = hi + 4 * r;
      outT[((b * Cc + c0 + cl) * Nn) + n0 + lo] = tile[lo][cl];
    }
  }
}

// ---------------------------------------------------------------------------
// Grouped 1x1 conv + ReLU + fused qt/kt projection.
// xT [B,C,N] -> out f32 [B,C,N] (full), gsm bf16 (= 0.25*sm*relu) written at
// COMPACTED columns (position of n among sm!=0 nodes, recomputed via ballots).
// qkt: oh==0 writes qt at compacted cols, pre-scaled by -log2e (+bias);
//      oh==1 writes kt at full cols, pre-scaled by -log2e.
// grid (N/64, 2, B), block 256 = 64 nodes x 4 (groups == heads).
// ---------------------------------------------------------------------------
__global__ __launch_bounds__(256) void k_gconvq(const float* __restrict__ xT,
                                                const float* __restrict__ cw,
                                                const float* __restrict__ cb,
                                                const float* __restrict__ sm,
                                                const float* __restrict__ spat,
                                                const float* __restrict__ W,
                                                const float* __restrict__ bias,
                                                float* __restrict__ out,
                                                __bf16* __restrict__ gsm,
                                                float* __restrict__ qt,
                                                float* __restrict__ kt) {
  __shared__ float xs[Cc][64];  // 64 KiB
  const int b = blockIdx.z, n0 = blockIdx.x * 64, oh = blockIdx.y;
  const int t = threadIdx.x;
  const int lo = t & 63, hi = t >> 6;
#pragma unroll 4
  for (int r = 0; r < 64; ++r) {
    int c = hi + 4 * r;
    xs[c][lo] = xT[((b * Cc + c) * Nn) + n0 + lo];
  }
  __syncthreads();
  const int g = hi, nl = lo, n = n0 + nl;

  // ---- compacted column position of node n (lane nl of each wave) ----
  unsigned long long am = 0;
  int cbase = 0;
  const int myc = blockIdx.x;  // n0 >> 6
  for (int jc = 0; jc <= myc; ++jc) {
    unsigned long long m = __ballot(sm[b * Nn + jc * 64 + nl] != 0.f);
    if (jc < myc) cbase += __popcll(m); else am = m;
  }
  const bool act = (am >> nl) & 1;
  const int pcol = cbase + __popcll(am & ((1ull << nl) - 1));

  // ---- qt/kt projection from the staged tile (oh picks q vs k) ----
  {
    const int h = hi;
    const float* wrow = W + h * WROW + oh * Cc;  // Wq or Wk
    float a = 0.f;
#pragma unroll 8
    for (int c = 0; c < Cc; ++c) a = fmaf(xs[c][nl], wrow[c], a);
    const float s0 = spat[(b * Nn + n) * 2 + 0];
    const float s1 = spat[(b * Nn + n) * 2 + 1];
    const float* wsp = W + h * WROW + 2 * Cc + oh * 2;  // Wsq or Wsk
    a += s0 * wsp[0] + s1 * wsp[1];
    if (oh == 0) {
      if (act)  // compacted, pre-scaled, bias folded
        qt[(b * Hh + h) * Nn + pcol] = (a + bias[h]) * -1.44269504f;
    } else {
      kt[(b * Hh + h) * Nn + n] = a * -1.44269504f;  // full, pre-scaled
    }
  }

  // ---- grouped conv ----
  const float smv = 0.25f * sm[b * Nn + n];
  float xv[64];
#pragma unroll
  for (int ci = 0; ci < 64; ++ci) xv[ci] = xs[g * 64 + ci][nl];
  const int obase = oh * 32;
  for (int oi = 0; oi < 32; ++oi) {
    const int co = g * 64 + obase + oi;
    float acc = cb[co];
    const float4* w4 = (const float4*)&cw[co * 64];
#pragma unroll
    for (int c4 = 0; c4 < 16; ++c4) {
      float4 w = w4[c4];
      acc = fmaf(w.x, xv[c4 * 4 + 0], acc);
      acc = fmaf(w.y, xv[c4 * 4 + 1], acc);
      acc = fmaf(w.z, xv[c4 * 4 + 2], acc);
      acc = fmaf(w.w, xv[c4 * 4 + 3], acc);
    }
    const float relu = fmaxf(acc, 0.f);
    const size_t orow = ((size_t)(b * Cc + co)) * Nn;
    out[orow + n0 + nl] = relu;
    if (act) gsm[orow + pcol] = (__bf16)(smv * relu);
  }
}

// ---------------------------------------------------------------------------
// MFMA fused attention apply, v7: K-COMPACTED (only sm!=0 columns, cnt~512).
// Per block (b, it, h): C[i,d] = 0.25*sum_j sig(qt[j]+kt[i])*mask[i,j]*G[d,j]
// cnt recomputed from sm (16 ballots); stepsTot = ceil(cnt/64);
// S = ceil(stepsTot/2). Group grp (waves 0-3 / 4-7) covers compacted chunks
// [grp*S, grp*S+S). Padding chunks have zero roib bits -> A=0 kills any
// stale/garbage B bytes (finite under 0xAA poison), so tails are inert.
// Staging: per-group private 3-buffer LDS ring, 2 GLLs/wave/step; dummy GLL
// (re-reads chunk c0 into the dead slot) on tail steps keeps the per-wave
// vmcnt count uniform so vmcnt(2) == "buf s landed" holds through the LAST
// step (fixes r8's latent final-step race). __syncthreads before the LDS
// reduction drains the in-flight dummies (compiler emits vmcnt(0)).
// grid dim3(8 b, 16 it, 4 h): linear%8 == b -> each XCD serves one batch.
// ---------------------------------------------------------------------------
template <int MODE>
__global__ __launch_bounds__(512, 4) void k_apply7(const float* __restrict__ g,
                                                   const __bf16* __restrict__ gsm,
                                                   const float* __restrict__ qt,
                                                   const float* __restrict__ kt,
                                                   const unsigned char* __restrict__ roib,
                                                   const float* __restrict__ sm,
                                                   float* __restrict__ out) {
  // [group][buf][kk][64 rows * 32 j] bf16 = 48KB
  __shared__ __align__(16) __bf16 Bs[2][3][2][2048];
  __shared__ __align__(16) float qts[1024];              // pre-scaled qt (4KB)
  __shared__ __align__(16) unsigned char rbs[64 * 128];  // roib rows (8KB)
  const int b = blockIdx.x, it = blockIdx.y, h = blockIdx.z;
  const int t = threadIdx.x, w = t >> 6, l = t & 63;
  const int grp = w >> 2, wq = w & 3;
  const int i0 = it * 64;
  const int dl = l & 15, q = l >> 4, jqf = q * 8;
  const int iA = i0 + wq * 16 + dl;

  const float kvn = kt[(b * Hh + h) * Nn + iA];  // pre-scaled by -log2e
  const float* smrow = sm + b * Nn;

  // ---- compacted-K extent (all waves recompute; sm is L2-hot) ----
  int cnt = 0;
#pragma unroll
  for (int jc = 0; jc < 16; ++jc)
    cnt += __popcll(__ballot(smrow[jc * 64 + l] != 0.f));
  const int stepsTot = (cnt + 63) >> 6;
  const int S = (stepsTot + 1) >> 1;  // steps per group (uniform across waves)
  const int c0 = grp * S;             // my group's first compacted chunk

  // GLL staging: wave (grp,wq) stages rows wq*16 + (l>>2), 8-j chunk (l&3)
  const __bf16* gsrc = gsm + ((size_t)(b * Cc + h * 64 + wq * 16 + (l >> 2))) * Nn
                       + c0 * 64 + (l & 3) * 8;
  __bf16* ring = &Bs[grp][0][0][0];
  const int wdst = wq * 512;

  // ---- prologue: stage qts (already scaled) + rbs, GLL chunks c0, c0+1 ----
  {
    const float2 qv = *(const float2*)&qt[(b * Hh + h) * Nn + t * 2];
    qts[t * 2 + 0] = qv.x;
    qts[t * 2 + 1] = qv.y;
  }
  {
    const int r = t >> 3, c = (t & 7) * 16;
    const char* src = (const char*)roib + ((size_t)(b * Nn + i0 + r)) * 128 + c;
    *(int4*)&rbs[r * 128 + c] = *(const int4*)src;
  }
  GLL16(gsrc, ring + 0 * 4096 + 0 * 2048 + wdst);
  GLL16(gsrc + 32, ring + 0 * 4096 + 1 * 2048 + wdst);
  GLL16(gsrc + 64, ring + 1 * 4096 + 0 * 2048 + wdst);
  GLL16(gsrc + 96, ring + 1 * 4096 + 1 * 2048 + wdst);
  __syncthreads();  // drains prologue GLLs + publishes qts/rbs

  const int rbbase = (wq * 16 + dl) * 128;
  f32x4 acc[4] = {};
  int cur = 0;  // s % 3

  // ---- main loop: S K-steps of 64 compacted j per wave ----
  for (int s = 0; s < S; ++s) {
    const int ck = c0 + s;
    // A-fragments (stable LDS data — safe before the barrier)
    const unsigned int rb0 = rbs[rbbase + ck * 8 + q];
    const unsigned int rb1 = rbs[rbbase + ck * 8 + 4 + q];
    bf16x8 af0, af1;
    {
      fx4 qa = *(const fx4*)&qts[ck * 64 + jqf];
      fx4 qb = *(const fx4*)&qts[ck * 64 + jqf + 4];
#pragma unroll
      for (int e = 0; e < 4; ++e) {
        float sg = __builtin_amdgcn_rcpf(1.f + __builtin_amdgcn_exp2f(qa[e] + kvn));
        af0[e] = (__bf16)(((rb0 >> e) & 1) ? sg : 0.f);
      }
#pragma unroll
      for (int e = 0; e < 4; ++e) {
        float sg = __builtin_amdgcn_rcpf(1.f + __builtin_amdgcn_exp2f(qb[e] + kvn));
        af0[4 + e] = (__bf16)(((rb0 >> (4 + e)) & 1) ? sg : 0.f);
      }
      fx4 qc = *(const fx4*)&qts[ck * 64 + 32 + jqf];
      fx4 qd = *(const fx4*)&qts[ck * 64 + 32 + jqf + 4];
#pragma unroll
      for (int e = 0; e < 4; ++e) {
        float sg = __builtin_amdgcn_rcpf(1.f + __builtin_amdgcn_exp2f(qc[e] + kvn));
        af1[e] = (__bf16)(((rb1 >> e) & 1) ? sg : 0.f);
      }
#pragma unroll
      for (int e = 0; e < 4; ++e) {
        float sg = __builtin_amdgcn_rcpf(1.f + __builtin_amdgcn_exp2f(qd[e] + kvn));
        af1[4 + e] = (__bf16)(((rb1 >> (4 + e)) & 1) ? sg : 0.f);
      }
    }
    // buf s landed iff <=2 outstanding (only the newest pair may remain)
    asm volatile("s_waitcnt vmcnt(2)\n\ts_barrier" ::: "memory");
    __builtin_amdgcn_sched_barrier(0);
    // prefetch step s+2 (or DUMMY chunk c0 into the dead slot — keeps the
    // per-wave vmcnt count uniform so the invariant holds at every step)
    {
      const int nc = s + 2;
      const int off = (nc < S) ? nc * 64 : 0;
      const int pf = (cur == 0) ? 2 : cur - 1;  // (s+2)%3
      GLL16(gsrc + off, ring + pf * 4096 + 0 * 2048 + wdst);
      GLL16(gsrc + off + 32, ring + pf * 4096 + 1 * 2048 + wdst);
    }
    // MFMA cluster on buf s
    const __bf16* bp = ring + cur * 4096;
#pragma unroll
    for (int nf = 0; nf < 4; ++nf) {
      bf16x8 bv = *(const bf16x8*)(bp + (nf * 16 + dl) * 32 + jqf);
      acc[nf] = __builtin_amdgcn_mfma_f32_16x16x32_bf16(af0, bv, acc[nf], 0, 0, 0);
    }
#pragma unroll
    for (int nf = 0; nf < 4; ++nf) {
      bf16x8 bv = *(const bf16x8*)(bp + 2048 + (nf * 16 + dl) * 32 + jqf);
      acc[nf] = __builtin_amdgcn_mfma_f32_16x16x32_bf16(af1, bv, acc[nf], 0, 0, 0);
    }
    cur = (cur == 2) ? 0 : cur + 1;
  }

  // ---- combine group partials through LDS (drained by __syncthreads) ----
  __syncthreads();
  float* accS = (float*)&Bs[0][0][0][0];  // 4 wq x 64 l x 4 nf x f32x4 = 16KB
  if (grp == 1) {
#pragma unroll
    for (int nf = 0; nf < 4; ++nf)
      *(f32x4*)&accS[((wq * 64 + l) * 4 + nf) * 4] = acc[nf];
  }
  __syncthreads();
  if (grp == 0) {
#pragma unroll
    for (int nf = 0; nf < 4; ++nf)
      acc[nf] += *(const f32x4*)&accS[((wq * 64 + l) * 4 + nf) * 4];

    // epilogue: D layout col(d)=lane&15, row(i)=(lane>>4)*4+reg
    const int iw = i0 + wq * 16 + (l >> 4) * 4;
    fx4 sv = *(const fx4*)&smrow[iw];
    float fv[4];
#pragma unroll
    for (int r = 0; r < 4; ++r) fv[r] = (sv[r] == 0.f) ? 0.25f : 0.f;
    if (MODE == 0) {
#pragma unroll
      for (int nf = 0; nf < 4; ++nf) {
        const int ch = h * 64 + nf * 16 + dl;
        const size_t base = ((size_t)(b * Cc + ch)) * Nn + iw;
        fx4 gv = *(const fx4*)&g[base];
        fx4 res;
#pragma unroll
        for (int r = 0; r < 4; ++r) res[r] = gv[r] * (1.f + fv[r]) + acc[nf][r];
        *(fx4*)&out[base] = res;
      }
    } else {
#pragma unroll
      for (int nf = 0; nf < 4; ++nf) {
        const int ch = h * 64 + nf * 16 + dl;
        fx4 gv = *(const fx4*)&g[((size_t)(b * Cc + ch)) * Nn + iw];
#pragma unroll
        for (int r = 0; r < 4; ++r)
          out[((size_t)b * Nn + iw + r) * Cc + ch] = acc[nf][r] + fv[r] * gv[r];
      }
    }
  }
}

// ---------------------------------------------------------------------------
// Fused LayerNorm stats + final residual add, one pass.
// io [B,N,C] (holds outm2T) updated in place:
//   y[b,i,c] = g2[b,c,i] + (io[b,i,c]-mu_i)*rstd_i*lng[c] + lnb[c]
// grid (8 b, 32 it), block 256 = 4 waves x 8 node-iters.
// ---------------------------------------------------------------------------
__global__ __launch_bounds__(256) void k_lnfinal(float* __restrict__ io,
                                                 const float* __restrict__ g2,
                                                 const float* __restrict__ lng,
                                                 const float* __restrict__ lnb) {
  __shared__ float gt[32][258];
  const int b = blockIdx.x, i0 = blockIdx.y * 32;
  const int t = threadIdx.x, w = t >> 6, l = t & 63;
  {
    const int n = t & 31, ch = t >> 5;
#pragma unroll 8
    for (int rr = 0; rr < 32; ++rr) {
      int c = rr * 8 + ch;
      gt[n][c] = g2[((size_t)(b * Cc + c)) * Nn + i0 + n];
    }
  }
  __syncthreads();
  const fx4 lngv = *(const fx4*)&lng[l * 4];
  const fx4 lnbv = *(const fx4*)&lnb[l * 4];
#pragma unroll
  for (int r = 0; r < 8; ++r) {
    const int n = r * 4 + w;
    const size_t base = ((size_t)(b * Nn) + i0 + n) * Cc + l * 4;
    fx4 v = *(const fx4*)&io[base];
    float s = v[0] + v[1] + v[2] + v[3];
    float sq = v[0] * v[0] + v[1] * v[1] + v[2] * v[2] + v[3] * v[3];
#pragma unroll
    for (int off = 32; off; off >>= 1) {
      s += __shfl_xor(s, off, 64);
      sq += __shfl_xor(sq, off, 64);
    }
    const float m = s * (1.f / 256.f);
    const float var = sq * (1.f / 256.f) - m * m;
    const float rstd = rsqrtf(fmaxf(var, 0.f) + 1e-6f);
    fx4 gv = *(const fx4*)&gt[n][l * 4];
    fx4 res;
#pragma unroll
    for (int e = 0; e < 4; ++e)
      res[e] = gv[e] + (v[e] - m) * rstd * lngv[e] + lnbv[e];
    *(fx4*)&io[base] = res;
  }
}

// ---------------------------------------------------------------------------
extern "C" void kernel_launch(void* const* d_in, const int* in_sizes, int n_in,
                              void* d_out, int out_size, void* d_ws, size_t ws_size,
                              hipStream_t stream) {
  (void)in_sizes; (void)n_in; (void)out_size; (void)ws_size;
  const float* input = (const float*)d_in[0];
  const float* roi   = (const float*)d_in[1];   // masks_roi [B,N,N]
  const float* sm    = (const float*)d_in[2];   // score_mask [B,N]
  const float* spat  = (const float*)d_in[3];
  const float* W1    = (const float*)d_in[4];
  const float* b1    = (const float*)d_in[5];
  const float* W2    = (const float*)d_in[6];
  const float* b2    = (const float*)d_in[7];
  const float* cw1   = (const float*)d_in[8];
  const float* cb1   = (const float*)d_in[9];
  const float* cw2   = (const float*)d_in[10];
  const float* cb2   = (const float*)d_in[11];
  const float* lng   = (const float*)d_in[12];
  const float* lnb   = (const float*)d_in[13];
  // d_in[14] = node_num: unused — scores[b,i,i]=1 is the strict row max, so
  // every column lands in some row's top-k and the `present` mask is all-ones.

  float* outf = (float*)d_out;
  char* ws = (char*)d_ws;
  const size_t PLANE = (size_t)Bb * Cc * Nn;  // 2M elements
  // ws layout (~12.8 MB):
  float* gbuf = (float*)ws;                              // conv out f32, 8MB
  __bf16* gsm = (__bf16*)(ws + PLANE * 4);               // 0.25*sm*g bf16, 4MB
  unsigned long long* roib =
      (unsigned long long*)(ws + PLANE * 4 + PLANE * 2); // 1MB (8192 rows x 128B)
  float* qtb = (float*)((char*)roib + (size_t)Bb * Nn * 128);
  float* ktb = qtb + Bb * Hh * Nn;
  // d_out doubles as scratch: holds x^T, then out1 [B,C,N], then final out.
  float* inT  = outf;
  float* out1 = outf;

  k_roitr<<<dim3(2560), 256, 0, stream>>>(roi, sm, roib, input, inT);
  k_gconvq<<<dim3(16, 2, 8), 256, 0, stream>>>(inT, cw1, cb1, sm, spat, W1, b1,
                                               gbuf, gsm, qtb, ktb);
  k_apply7<0><<<dim3(8, 16, 4), 512, 0, stream>>>(gbuf, gsm, qtb, ktb,
                                                  (const unsigned char*)roib, sm, out1);
  k_gconvq<<<dim3(16, 2, 8), 256, 0, stream>>>(out1, cw2, cb2, sm, spat, W2, b2,
                                               gbuf, gsm, qtb, ktb);
  k_apply7<1><<<dim3(8, 16, 4), 512, 0, stream>>>(gbuf, gsm, qtb, ktb,
                                                  (const unsigned char*)roib, sm, outf);
  k_lnfinal<<<dim3(8, 32), 256, 0, stream>>>(outf, gbuf, lng, lnb);
}

// Round 11
// 76.586 us; speedup vs baseline: 3.8819x; 1.5988x over previous
//
#include <hip/hip_runtime.h>

constexpr int Bb = 8;     // batch
constexpr int Nn = 1024;  // nodes
constexpr int Cc = 256;   // channels
constexpr int Hh = 4;     // heads
constexpr int WROW = 2 * Cc + 4;  // 516, same for W1 and W2

typedef float fx4 __attribute__((ext_vector_type(4)));
typedef float f32x4 __attribute__((ext_vector_type(4)));
typedef __bf16 bf16x8 __attribute__((ext_vector_type(8)));

#define GLL16(src, dst)                                                      \
  __builtin_amdgcn_global_load_lds(                                          \
      (const __attribute__((address_space(1))) void*)(src),                  \
      (__attribute__((address_space(3))) void*)(dst), 16, 0, 0)

// ---------------------------------------------------------------------------
// roipack: pack roi bits over COMPACTED j (order-preserving list of j with
// sm[b,j]!=0, built locally via 16 ballots) into roib [B*N][16] u64.
// Words beyond ceil(cnt/64) are zero. grid 2048, block 256 (4 rows/block).
// ---------------------------------------------------------------------------
__global__ __launch_bounds__(256) void k_roipack(const float* __restrict__ roi,
                                                 const float* __restrict__ sm,
                                                 unsigned long long* __restrict__ roib) {
  __shared__ short jmapS[1024];
  __shared__ int cntS;
  const int t = threadIdx.x;
  const int gid = blockIdx.x * 4 + (t >> 6);  // row over B*N (4 rows, same b)
  const int b = gid >> 10;
  const int l = t & 63;
  if ((t >> 6) == 0) {
    int base = 0;
#pragma unroll
    for (int jc = 0; jc < 16; ++jc) {
      const int j = jc * 64 + l;
      const bool act = sm[b * Nn + j] != 0.f;
      const unsigned long long m = __ballot(act);
      if (act) jmapS[base + __popcll(m & ((1ull << l) - 1))] = (short)j;
      base += __popcll(m);
    }
    if (l == 0) cntS = base;
  }
  __syncthreads();
  const int cnt = cntS;
  const float* rrow = roi + (size_t)gid * Nn;
  unsigned long long* orow = roib + (size_t)gid * 16;
#pragma unroll 4
  for (int pc = 0; pc < 16; ++pc) {
    const int idx = pc * 64 + l;
    const bool valid = idx < cnt;
    const int j = valid ? jmapS[idx] : 0;
    const bool bit = valid && (rrow[j] != 0.f);
    unsigned long long m = __ballot(bit);
    if (l == 0) orow[pc] = m;
  }
}

// ---------------------------------------------------------------------------
// Grouped 1x1 conv (MFMA) + ReLU + fused qt/kt projection.
// Stages one bf16 tile xsB[32 nodes][256 c] straight from the source
// (STAGE 0: input [B,N,C]; STAGE 1: out1 [B,C,N]). xsB stored as 32 chunks
// of bf16x8 per row, chunk XOR-swizzled by (n&7).
// Conv: wave g computes D[64 co x 32 n] = cw_g[64x64] . x_g[64x32] via
// 16 mfma_16x16x32. BUGFIX r10: the B-fragment chunk index must include the
// GROUP offset g*8 — group g's input channels are chunks g*8..g*8+7 of xsB
// (r10 read chunks 0..7 for every group -> absmax 11.2).
// qkt: wave g = head g, 2 lanes per node split the 256-c dot, shfl_xor(32)
// combines; qt written at compacted cols pre-scaled by -log2e (+bias),
// kt full cols pre-scaled. Outputs: gbuf f32, gsm bf16 (0.25*sm*relu).
// grid (8 b, 32 node-tiles), block 256 = 4 waves (wave == group == head).
// ---------------------------------------------------------------------------
template <int STAGE>
__global__ __launch_bounds__(256) void k_gconvq(const float* __restrict__ src,
                                                const float* __restrict__ cw,
                                                const float* __restrict__ cb,
                                                const float* __restrict__ sm,
                                                const float* __restrict__ spat,
                                                const float* __restrict__ W,
                                                const float* __restrict__ bias,
                                                float* __restrict__ out,
                                                __bf16* __restrict__ gsm,
                                                float* __restrict__ qt,
                                                float* __restrict__ kt) {
  __shared__ __align__(16) bf16x8 xsB[32][32];  // [node][c-chunk^swz] 16KB
  __shared__ float cbS[256];
  __shared__ float smS[32];
  __shared__ int pcolS[32];
  __shared__ int actS[32];
  const int b = blockIdx.x, tile = blockIdx.y;
  const int n0 = tile * 32;
  const int t = threadIdx.x, w = t >> 6, l = t & 63;

  // ---- wave 0: compacted-column positions for this tile's 32 nodes ----
  if (w == 0) {
    const int fullc = n0 >> 6;
    int cbase = 0;
    unsigned long long am = 0;
    for (int jc = 0; jc <= fullc; ++jc) {
      unsigned long long m = __ballot(sm[b * Nn + jc * 64 + l] != 0.f);
      if (jc < fullc) cbase += __popcll(m); else am = m;
    }
    const int lsel = l - (n0 & 63);
    if (lsel >= 0 && lsel < 32) {
      pcolS[lsel] = cbase + __popcll(am & ((1ull << l) - 1));
      actS[lsel] = (int)((am >> l) & 1);
      smS[lsel] = 0.25f * sm[b * Nn + n0 + lsel];
    }
  }
  cbS[t] = cb[t];

  // ---- stage tile into xsB (bf16, chunk-swizzled) ----
  if (STAGE == 0) {
    // src = input [B,N,C]: thread t loads node n = t>>3, c-chunk (t&7)*32
    const int n = t >> 3, c0 = (t & 7) * 32;
    const float* srow = src + ((size_t)(b * Nn + n0 + n)) * Cc + c0;
#pragma unroll
    for (int k = 0; k < 4; ++k) {
      fx4 v0 = *(const fx4*)&srow[k * 8];
      fx4 v1 = *(const fx4*)&srow[k * 8 + 4];
      bf16x8 bv;
#pragma unroll
      for (int e = 0; e < 4; ++e) { bv[e] = (__bf16)v0[e]; bv[4 + e] = (__bf16)v1[e]; }
      xsB[n][((c0 >> 3) + k) ^ (n & 7)] = bv;
    }
  } else {
    // src = out1 [B,C,N]: 8 rounds, 32 c-rows per round, fx4 of 4 nodes
#pragma unroll
    for (int rr = 0; rr < 8; ++rr) {
      const int c = rr * 32 + (t >> 3);
      const int nq = (t & 7) * 4;
      fx4 v = *(const fx4*)&src[((size_t)(b * Cc + c)) * Nn + n0 + nq];
#pragma unroll
      for (int j = 0; j < 4; ++j) {
        const int n = nq + j;
        __bf16* row = (__bf16*)&xsB[n][(c >> 3) ^ (n & 7)];
        row[c & 7] = (__bf16)v[j];
      }
    }
  }
  __syncthreads();

  const int g = w, dl = l & 15, q = l >> 4;

  // ---- conv via MFMA: A = cw_g rows (bf16), B = xsB rows (group-g chunks) ----
  bf16x8 a[4][2];
#pragma unroll
  for (int of = 0; of < 4; ++of)
#pragma unroll
    for (int ks = 0; ks < 2; ++ks) {
      const float* cwp = cw + ((size_t)(g * 64 + of * 16 + dl)) * 64 + ks * 32 + q * 8;
      fx4 c0 = *(const fx4*)cwp;
      fx4 c1 = *(const fx4*)(cwp + 4);
#pragma unroll
      for (int e = 0; e < 4; ++e) { a[of][ks][e] = (__bf16)c0[e]; a[of][ks][4 + e] = (__bf16)c1[e]; }
    }
  f32x4 acc[4][2] = {};
#pragma unroll
  for (int nf = 0; nf < 2; ++nf) {
    const int n = nf * 16 + dl;
#pragma unroll
    for (int ks = 0; ks < 2; ++ks) {
      // group g's input channels are xsB chunks g*8 .. g*8+7  (r10 BUGFIX)
      bf16x8 bv = xsB[n][(g * 8 + ks * 4 + q) ^ (n & 7)];
#pragma unroll
      for (int of = 0; of < 4; ++of)
        acc[of][nf] = __builtin_amdgcn_mfma_f32_16x16x32_bf16(a[of][ks], bv, acc[of][nf], 0, 0, 0);
    }
  }
  // epilogue: D row = 4q+r -> co, col = dl -> node
#pragma unroll
  for (int of = 0; of < 4; ++of)
#pragma unroll
    for (int nf = 0; nf < 2; ++nf) {
      const int n = nf * 16 + dl;
      const float smv = smS[n];
      const int act = actS[n];
      const int pc = pcolS[n];
#pragma unroll
      for (int r = 0; r < 4; ++r) {
        const int co = g * 64 + of * 16 + 4 * q + r;
        const float val = fmaxf(acc[of][nf][r] + cbS[co], 0.f);
        const size_t orow = ((size_t)(b * Cc + co)) * Nn;
        out[orow + n0 + n] = val;
        if (act) gsm[orow + pc] = (__bf16)(smv * val);
      }
    }

  // ---- qt/kt projection: 2 lanes per node, split-C + shfl combine ----
  {
    const int nl = l & 31, half = l >> 5;
    const float* wq = W + g * WROW;
    const float* wk = wq + Cc;
    float qa = 0.f, ka = 0.f;
#pragma unroll 8
    for (int c2 = 0; c2 < 64; ++c2) {
      const int c = half * 128 + c2 * 2;
      const __bf16* p = (const __bf16*)&xsB[nl][(c >> 3) ^ (nl & 7)] + (c & 7);
      const float x0 = (float)p[0], x1 = (float)p[1];
      qa = fmaf(x0, wq[c], fmaf(x1, wq[c + 1], qa));
      ka = fmaf(x0, wk[c], fmaf(x1, wk[c + 1], ka));
    }
    qa += __shfl_xor(qa, 32, 64);
    ka += __shfl_xor(ka, 32, 64);
    if (l < 32) {
      const int n = n0 + nl;
      const float s0 = spat[(b * Nn + n) * 2 + 0];
      const float s1 = spat[(b * Nn + n) * 2 + 1];
      const float* wsp = W + g * WROW + 2 * Cc;
      const float qf = qa + s0 * wsp[0] + s1 * wsp[1] + bias[g];
      const float kf = ka + s0 * wsp[2] + s1 * wsp[3];
      kt[(b * Hh + g) * Nn + n] = kf * -1.44269504f;
      if (actS[nl]) qt[(b * Hh + g) * Nn + pcolS[nl]] = qf * -1.44269504f;
    }
  }
}

// ---------------------------------------------------------------------------
// MFMA fused attention apply, v7 (unchanged from r9 — proven).
// Per block (b, it, h): C[i,d] = 0.25*sum_j sig(qt[j]+kt[i])*mask[i,j]*G[d,j]
// K-compacted; per-group private 3-buffer LDS ring; 2 GLLs/wave/step with
// uniform dummy-GLL tail so vmcnt(2) == "buf s landed" at every step.
// grid dim3(8 b, 16 it, 4 h): linear%8 == b -> each XCD serves one batch.
// ---------------------------------------------------------------------------
template <int MODE>
__global__ __launch_bounds__(512, 4) void k_apply7(const float* __restrict__ g,
                                                   const __bf16* __restrict__ gsm,
                                                   const float* __restrict__ qt,
                                                   const float* __restrict__ kt,
                                                   const unsigned char* __restrict__ roib,
                                                   const float* __restrict__ sm,
                                                   float* __restrict__ out) {
  __shared__ __align__(16) __bf16 Bs[2][3][2][2048];
  __shared__ __align__(16) float qts[1024];
  __shared__ __align__(16) unsigned char rbs[64 * 128];
  const int b = blockIdx.x, it = blockIdx.y, h = blockIdx.z;
  const int t = threadIdx.x, w = t >> 6, l = t & 63;
  const int grp = w >> 2, wq = w & 3;
  const int i0 = it * 64;
  const int dl = l & 15, q = l >> 4, jqf = q * 8;
  const int iA = i0 + wq * 16 + dl;

  const float kvn = kt[(b * Hh + h) * Nn + iA];  // pre-scaled by -log2e
  const float* smrow = sm + b * Nn;

  int cnt = 0;
#pragma unroll
  for (int jc = 0; jc < 16; ++jc)
    cnt += __popcll(__ballot(smrow[jc * 64 + l] != 0.f));
  const int stepsTot = (cnt + 63) >> 6;
  const int S = (stepsTot + 1) >> 1;
  const int c0 = grp * S;

  const __bf16* gsrc = gsm + ((size_t)(b * Cc + h * 64 + wq * 16 + (l >> 2))) * Nn
                       + c0 * 64 + (l & 3) * 8;
  __bf16* ring = &Bs[grp][0][0][0];
  const int wdst = wq * 512;

  {
    const float2 qv = *(const float2*)&qt[(b * Hh + h) * Nn + t * 2];
    qts[t * 2 + 0] = qv.x;
    qts[t * 2 + 1] = qv.y;
  }
  {
    const int r = t >> 3, c = (t & 7) * 16;
    const char* src = (const char*)roib + ((size_t)(b * Nn + i0 + r)) * 128 + c;
    *(int4*)&rbs[r * 128 + c] = *(const int4*)src;
  }
  GLL16(gsrc, ring + 0 * 4096 + 0 * 2048 + wdst);
  GLL16(gsrc + 32, ring + 0 * 4096 + 1 * 2048 + wdst);
  GLL16(gsrc + 64, ring + 1 * 4096 + 0 * 2048 + wdst);
  GLL16(gsrc + 96, ring + 1 * 4096 + 1 * 2048 + wdst);
  __syncthreads();

  const int rbbase = (wq * 16 + dl) * 128;
  f32x4 acc[4] = {};
  int cur = 0;

  for (int s = 0; s < S; ++s) {
    const int ck = c0 + s;
    const unsigned int rb0 = rbs[rbbase + ck * 8 + q];
    const unsigned int rb1 = rbs[rbbase + ck * 8 + 4 + q];
    bf16x8 af0, af1;
    {
      fx4 qa = *(const fx4*)&qts[ck * 64 + jqf];
      fx4 qb = *(const fx4*)&qts[ck * 64 + jqf + 4];
#pragma unroll
      for (int e = 0; e < 4; ++e) {
        float sg = __builtin_amdgcn_rcpf(1.f + __builtin_amdgcn_exp2f(qa[e] + kvn));
        af0[e] = (__bf16)(((rb0 >> e) & 1) ? sg : 0.f);
      }
#pragma unroll
      for (int e = 0; e < 4; ++e) {
        float sg = __builtin_amdgcn_rcpf(1.f + __builtin_amdgcn_exp2f(qb[e] + kvn));
        af0[4 + e] = (__bf16)(((rb0 >> (4 + e)) & 1) ? sg : 0.f);
      }
      fx4 qc = *(const fx4*)&qts[ck * 64 + 32 + jqf];
      fx4 qd = *(const fx4*)&qts[ck * 64 + 32 + jqf + 4];
#pragma unroll
      for (int e = 0; e < 4; ++e) {
        float sg = __builtin_amdgcn_rcpf(1.f + __builtin_amdgcn_exp2f(qc[e] + kvn));
        af1[e] = (__bf16)(((rb1 >> e) & 1) ? sg : 0.f);
      }
#pragma unroll
      for (int e = 0; e < 4; ++e) {
        float sg = __builtin_amdgcn_rcpf(1.f + __builtin_amdgcn_exp2f(qd[e] + kvn));
        af1[4 + e] = (__bf16)(((rb1 >> (4 + e)) & 1) ? sg : 0.f);
      }
    }
    asm volatile("s_waitcnt vmcnt(2)\n\ts_barrier" ::: "memory");
    __builtin_amdgcn_sched_barrier(0);
    {
      const int nc = s + 2;
      const int off = (nc < S) ? nc * 64 : 0;
      const int pf = (cur == 0) ? 2 : cur - 1;
      GLL16(gsrc + off, ring + pf * 4096 + 0 * 2048 + wdst);
      GLL16(gsrc + off + 32, ring + pf * 4096 + 1 * 2048 + wdst);
    }
    const __bf16* bp = ring + cur * 4096;
#pragma unroll
    for (int nf = 0; nf < 4; ++nf) {
      bf16x8 bv = *(const bf16x8*)(bp + (nf * 16 + dl) * 32 + jqf);
      acc[nf] = __builtin_amdgcn_mfma_f32_16x16x32_bf16(af0, bv, acc[nf], 0, 0, 0);
    }
#pragma unroll
    for (int nf = 0; nf < 4; ++nf) {
      bf16x8 bv = *(const bf16x8*)(bp + 2048 + (nf * 16 + dl) * 32 + jqf);
      acc[nf] = __builtin_amdgcn_mfma_f32_16x16x32_bf16(af1, bv, acc[nf], 0, 0, 0);
    }
    cur = (cur == 2) ? 0 : cur + 1;
  }

  __syncthreads();
  float* accS = (float*)&Bs[0][0][0][0];
  if (grp == 1) {
#pragma unroll
    for (int nf = 0; nf < 4; ++nf)
      *(f32x4*)&accS[((wq * 64 + l) * 4 + nf) * 4] = acc[nf];
  }
  __syncthreads();
  if (grp == 0) {
#pragma unroll
    for (int nf = 0; nf < 4; ++nf)
      acc[nf] += *(const f32x4*)&accS[((wq * 64 + l) * 4 + nf) * 4];

    const int iw = i0 + wq * 16 + (l >> 4) * 4;
    fx4 sv = *(const fx4*)&smrow[iw];
    float fv[4];
#pragma unroll
    for (int r = 0; r < 4; ++r) fv[r] = (sv[r] == 0.f) ? 0.25f : 0.f;
    if (MODE == 0) {
#pragma unroll
      for (int nf = 0; nf < 4; ++nf) {
        const int ch = h * 64 + nf * 16 + dl;
        const size_t base = ((size_t)(b * Cc + ch)) * Nn + iw;
        fx4 gv = *(const fx4*)&g[base];
        fx4 res;
#pragma unroll
        for (int r = 0; r < 4; ++r) res[r] = gv[r] * (1.f + fv[r]) + acc[nf][r];
        *(fx4*)&out[base] = res;
      }
    } else {
#pragma unroll
      for (int nf = 0; nf < 4; ++nf) {
        const int ch = h * 64 + nf * 16 + dl;
        fx4 gv = *(const fx4*)&g[((size_t)(b * Cc + ch)) * Nn + iw];
#pragma unroll
        for (int r = 0; r < 4; ++r)
          out[((size_t)b * Nn + iw + r) * Cc + ch] = acc[nf][r] + fv[r] * gv[r];
      }
    }
  }
}

// ---------------------------------------------------------------------------
// Fused LayerNorm stats + final residual add, one pass (unchanged).
// ---------------------------------------------------------------------------
__global__ __launch_bounds__(256) void k_lnfinal(float* __restrict__ io,
                                                 const float* __restrict__ g2,
                                                 const float* __restrict__ lng,
                                                 const float* __restrict__ lnb) {
  __shared__ float gt[32][258];
  const int b = blockIdx.x, i0 = blockIdx.y * 32;
  const int t = threadIdx.x, w = t >> 6, l = t & 63;
  {
    const int n = t & 31, ch = t >> 5;
#pragma unroll 8
    for (int rr = 0; rr < 32; ++rr) {
      int c = rr * 8 + ch;
      gt[n][c] = g2[((size_t)(b * Cc + c)) * Nn + i0 + n];
    }
  }
  __syncthreads();
  const fx4 lngv = *(const fx4*)&lng[l * 4];
  const fx4 lnbv = *(const fx4*)&lnb[l * 4];
#pragma unroll
  for (int r = 0; r < 8; ++r) {
    const int n = r * 4 + w;
    const size_t base = ((size_t)(b * Nn) + i0 + n) * Cc + l * 4;
    fx4 v = *(const fx4*)&io[base];
    float s = v[0] + v[1] + v[2] + v[3];
    float sq = v[0] * v[0] + v[1] * v[1] + v[2] * v[2] + v[3] * v[3];
#pragma unroll
    for (int off = 32; off; off >>= 1) {
      s += __shfl_xor(s, off, 64);
      sq += __shfl_xor(sq, off, 64);
    }
    const float m = s * (1.f / 256.f);
    const float var = sq * (1.f / 256.f) - m * m;
    const float rstd = rsqrtf(fmaxf(var, 0.f) + 1e-6f);
    fx4 gv = *(const fx4*)&gt[n][l * 4];
    fx4 res;
#pragma unroll
    for (int e = 0; e < 4; ++e)
      res[e] = gv[e] + (v[e] - m) * rstd * lngv[e] + lnbv[e];
    *(fx4*)&io[base] = res;
  }
}

// ---------------------------------------------------------------------------
extern "C" void kernel_launch(void* const* d_in, const int* in_sizes, int n_in,
                              void* d_out, int out_size, void* d_ws, size_t ws_size,
                              hipStream_t stream) {
  (void)in_sizes; (void)n_in; (void)out_size; (void)ws_size;
  const float* input = (const float*)d_in[0];
  const float* roi   = (const float*)d_in[1];   // masks_roi [B,N,N]
  const float* sm    = (const float*)d_in[2];   // score_mask [B,N]
  const float* spat  = (const float*)d_in[3];
  const float* W1    = (const float*)d_in[4];
  const float* b1    = (const float*)d_in[5];
  const float* W2    = (const float*)d_in[6];
  const float* b2    = (const float*)d_in[7];
  const float* cw1   = (const float*)d_in[8];
  const float* cb1   = (const float*)d_in[9];
  const float* cw2   = (const float*)d_in[10];
  const float* cb2   = (const float*)d_in[11];
  const float* lng   = (const float*)d_in[12];
  const float* lnb   = (const float*)d_in[13];
  // d_in[14] = node_num: unused — scores[b,i,i]=1 is the strict row max, so
  // every column lands in some row's top-k and the `present` mask is all-ones.

  float* outf = (float*)d_out;
  char* ws = (char*)d_ws;
  const size_t PLANE = (size_t)Bb * Cc * Nn;  // 2M elements
  float* gbuf = (float*)ws;                              // conv out f32, 8MB
  __bf16* gsm = (__bf16*)(ws + PLANE * 4);               // 0.25*sm*g bf16, 4MB
  unsigned long long* roib =
      (unsigned long long*)(ws + PLANE * 4 + PLANE * 2); // 1MB (8192 rows x 128B)
  float* qtb = (float*)((char*)roib + (size_t)Bb * Nn * 128);
  float* ktb = qtb + Bb * Hh * Nn;
  // d_out doubles as scratch: holds out1 [B,C,N] (apply1), then final out.
  float* out1 = outf;

  k_roipack<<<dim3(2048), 256, 0, stream>>>(roi, sm, roib);
  k_gconvq<0><<<dim3(8, 32), 256, 0, stream>>>(input, cw1, cb1, sm, spat, W1, b1,
                                               gbuf, gsm, qtb, ktb);
  k_apply7<0><<<dim3(8, 16, 4), 512, 0, stream>>>(gbuf, gsm, qtb, ktb,
                                                  (const unsigned char*)roib, sm, out1);
  k_gconvq<1><<<dim3(8, 32), 256, 0, stream>>>(out1, cw2, cb2, sm, spat, W2, b2,
                                               gbuf, gsm, qtb, ktb);
  k_apply7<1><<<dim3(8, 16, 4), 512, 0, stream>>>(gbuf, gsm, qtb, ktb,
                                                  (const unsigned char*)roib, sm, outf);
  k_lnfinal<<<dim3(8, 32), 256, 0, stream>>>(outf, gbuf, lng, lnb);
}